// Round 1
// baseline (1341.456 us; speedup 1.0000x reference)
//
#include <hip/hip_runtime.h>
#include <hip/hip_bf16.h>
#include <math.h>

#define S_LEN   2048
#define D_MODEL 1024
#define NH      16
#define DH      64
#define BATCH   2

// -------------------------------------------------------------------------
// Kernel 1: QKV projection.  C[m][n] = sum_d X[m][d] * W[n][d]   (C = X * W^T)
// X: [4096, 1024] row-major (b*2048+s, d).  W: [1024, 1024] row-major (h*64+e, d).
// Output scattered to q/k/v buffers in [b, h, s, e] layout for attention.
// 64x64 tile, 256 threads, 4x4 microtile, BK=16.
// -------------------------------------------------------------------------
__global__ __launch_bounds__(256) void qkv_kernel(
    const float* __restrict__ X,
    const float* __restrict__ WQ,
    const float* __restrict__ WK,
    const float* __restrict__ WV,
    float* __restrict__ qb, float* __restrict__ kb, float* __restrict__ vb)
{
    const float* W;
    float* outb;
    if (blockIdx.z == 0)      { W = WQ; outb = qb; }
    else if (blockIdx.z == 1) { W = WK; outb = kb; }
    else                      { W = WV; outb = vb; }

    __shared__ float As[16][64];   // [k][m]
    __shared__ float Bs[16][64];   // [k][n]

    const int m0  = blockIdx.x * 64;
    const int n0  = blockIdx.y * 64;
    const int tid = threadIdx.x;
    const int tx  = tid & 15;
    const int ty  = tid >> 4;

    const int lr = tid >> 2;         // 0..63 row within tile
    const int lk = (tid & 3) * 4;    // 0,4,8,12 k-offset

    float acc[4][4] = {};

    for (int k0 = 0; k0 < D_MODEL; k0 += 16) {
        float4 a = *(const float4*)(X + (size_t)(m0 + lr) * D_MODEL + k0 + lk);
        float4 b = *(const float4*)(W + (size_t)(n0 + lr) * D_MODEL + k0 + lk);
        As[lk + 0][lr] = a.x; As[lk + 1][lr] = a.y;
        As[lk + 2][lr] = a.z; As[lk + 3][lr] = a.w;
        Bs[lk + 0][lr] = b.x; Bs[lk + 1][lr] = b.y;
        Bs[lk + 2][lr] = b.z; Bs[lk + 3][lr] = b.w;
        __syncthreads();
        #pragma unroll
        for (int kk = 0; kk < 16; ++kk) {
            float av[4], bv[4];
            #pragma unroll
            for (int i = 0; i < 4; ++i) av[i] = As[kk][ty * 4 + i];
            #pragma unroll
            for (int j = 0; j < 4; ++j) bv[j] = Bs[kk][tx * 4 + j];
            #pragma unroll
            for (int i = 0; i < 4; ++i)
                #pragma unroll
                for (int j = 0; j < 4; ++j)
                    acc[i][j] += av[i] * bv[j];
        }
        __syncthreads();
    }

    // scatter write: row m -> (b, s); col n -> (h, e); out[b][h][s][e]
    const int h = n0 >> 6;   // n0 is a multiple of 64, tile spans exactly one head
    #pragma unroll
    for (int i = 0; i < 4; ++i) {
        const int m  = m0 + ty * 4 + i;
        const int bb = m >> 11;     // /2048
        const int s  = m & 2047;
        const int e  = tx * 4;
        float4 o = make_float4(acc[i][0], acc[i][1], acc[i][2], acc[i][3]);
        *(float4*)(outb + ((size_t)(bb * NH + h) * S_LEN + s) * DH + e) = o;
    }
}

// -------------------------------------------------------------------------
// Kernel 2: causal flash attention, fp32.
// grid: (qtile 0..31, bh 0..31), block 256 (16x16 logical, 4x4 microtile).
// Q pre-scaled by 1/8.  m/l live in registers (replicated across the 16
// threads of a row, kept consistent via shfl reductions).
// LDS: Qs/Ks/Vs 64x64 each with row-rotate swizzle (no padding) = 48 KB.
// P tile reuses Ks storage after scores are consumed.
// -------------------------------------------------------------------------
__global__ __launch_bounds__(256) void flash_kernel(
    const float* __restrict__ qb,
    const float* __restrict__ kb,
    const float* __restrict__ vb,
    float* __restrict__ attn)   // [B, S, H*DH]
{
    __shared__ float Qs[64][64];   // swizzled: Qs[r][(c + r) & 63]
    __shared__ float Ks[64][64];   // swizzled; reused for P tile
    __shared__ float Vs[64][64];   // plain

    const int qt  = blockIdx.x;    // q-tile
    const int bh  = blockIdx.y;    // b*16 + h
    const int tid = threadIdx.x;
    const int tx  = tid & 15;
    const int ty  = tid >> 4;

    const float* Qp = qb + (size_t)bh * S_LEN * DH;
    const float* Kp = kb + (size_t)bh * S_LEN * DH;
    const float* Vp = vb + (size_t)bh * S_LEN * DH;

    const int lrow = tid >> 2;            // 0..63
    const int lc0  = (tid & 3) * 16;      // 0,16,32,48

    // load Q tile, pre-scaled by 1/sqrt(64)
    {
        const float* src = Qp + (size_t)(qt * 64 + lrow) * DH + lc0;
        #pragma unroll
        for (int u = 0; u < 4; ++u) {
            float4 v = *(const float4*)(src + u * 4);
            int c = lc0 + u * 4;
            Qs[lrow][(c + 0 + lrow) & 63] = v.x * 0.125f;
            Qs[lrow][(c + 1 + lrow) & 63] = v.y * 0.125f;
            Qs[lrow][(c + 2 + lrow) & 63] = v.z * 0.125f;
            Qs[lrow][(c + 3 + lrow) & 63] = v.w * 0.125f;
        }
    }

    float acc[4][4] = {};
    float mi[4], li[4];
    #pragma unroll
    for (int i = 0; i < 4; ++i) { mi[i] = -1e30f; li[i] = 0.0f; }

    const int r0 = ty * 4;   // this thread's rows
    const int c0 = tx * 4;   // this thread's cols

    for (int kt = 0; kt <= qt; ++kt) {
        __syncthreads();   // previous iteration done reading Ks(P)/Vs; Qs ready gate below
        {
            const float* ksrc = Kp + (size_t)(kt * 64 + lrow) * DH + lc0;
            const float* vsrc = Vp + (size_t)(kt * 64 + lrow) * DH + lc0;
            #pragma unroll
            for (int u = 0; u < 4; ++u) {
                float4 k4 = *(const float4*)(ksrc + u * 4);
                float4 v4 = *(const float4*)(vsrc + u * 4);
                int c = lc0 + u * 4;
                Ks[lrow][(c + 0 + lrow) & 63] = k4.x;
                Ks[lrow][(c + 1 + lrow) & 63] = k4.y;
                Ks[lrow][(c + 2 + lrow) & 63] = k4.z;
                Ks[lrow][(c + 3 + lrow) & 63] = k4.w;
                Vs[lrow][c + 0] = v4.x;
                Vs[lrow][c + 1] = v4.y;
                Vs[lrow][c + 2] = v4.z;
                Vs[lrow][c + 3] = v4.w;
            }
        }
        __syncthreads();

        // S = Q * K^T  (scores for rows r0.., cols c0..)
        float sv[4][4] = {};
        for (int e = 0; e < 64; ++e) {
            float qv[4], kv[4];
            #pragma unroll
            for (int i = 0; i < 4; ++i) qv[i] = Qs[r0 + i][(e + r0 + i) & 63];
            #pragma unroll
            for (int j = 0; j < 4; ++j) kv[j] = Ks[c0 + j][(e + c0 + j) & 63];
            #pragma unroll
            for (int i = 0; i < 4; ++i)
                #pragma unroll
                for (int j = 0; j < 4; ++j)
                    sv[i][j] += qv[i] * kv[j];
        }

        // causal mask on the diagonal tile
        if (kt == qt) {
            #pragma unroll
            for (int i = 0; i < 4; ++i)
                #pragma unroll
                for (int j = 0; j < 4; ++j)
                    if (c0 + j > r0 + i) sv[i][j] = -1e30f;
        }

        // online softmax per row (replicated across the 16 row-threads)
        float alpha[4];
        #pragma unroll
        for (int i = 0; i < 4; ++i) {
            float rmax = fmaxf(fmaxf(sv[i][0], sv[i][1]), fmaxf(sv[i][2], sv[i][3]));
            #pragma unroll
            for (int off = 1; off < 16; off <<= 1)
                rmax = fmaxf(rmax, __shfl_xor(rmax, off, 16));
            float mnew = fmaxf(mi[i], rmax);
            alpha[i] = __expf(mi[i] - mnew);
            float rsum = 0.0f;
            #pragma unroll
            for (int j = 0; j < 4; ++j) {
                sv[i][j] = __expf(sv[i][j] - mnew);
                rsum += sv[i][j];
            }
            #pragma unroll
            for (int off = 1; off < 16; off <<= 1)
                rsum += __shfl_xor(rsum, off, 16);
            li[i] = li[i] * alpha[i] + rsum;
            mi[i] = mnew;
            #pragma unroll
            for (int j = 0; j < 4; ++j) acc[i][j] *= alpha[i];
        }

        __syncthreads();   // all waves done reading Ks as scores input
        // write P into Ks storage (same row-rotate swizzle)
        #pragma unroll
        for (int i = 0; i < 4; ++i)
            #pragma unroll
            for (int j = 0; j < 4; ++j)
                Ks[r0 + i][(c0 + j + r0 + i) & 63] = sv[i][j];
        __syncthreads();   // P visible

        // acc += P * V
        for (int kk = 0; kk < 64; ++kk) {
            float pv[4], vv[4];
            #pragma unroll
            for (int i = 0; i < 4; ++i) pv[i] = Ks[r0 + i][(kk + r0 + i) & 63];
            #pragma unroll
            for (int j = 0; j < 4; ++j) vv[j] = Vs[kk][c0 + j];
            #pragma unroll
            for (int i = 0; i < 4; ++i)
                #pragma unroll
                for (int j = 0; j < 4; ++j)
                    acc[i][j] += pv[i] * vv[j];
        }
    }

    // write attn[b, s, h*64 + e]
    const int b = bh >> 4;
    const int h = bh & 15;
    #pragma unroll
    for (int i = 0; i < 4; ++i) {
        const int s  = qt * 64 + r0 + i;
        const float inv = 1.0f / li[i];
        float4 o = make_float4(acc[i][0] * inv, acc[i][1] * inv,
                               acc[i][2] * inv, acc[i][3] * inv);
        *(float4*)(attn + (size_t)(b * S_LEN + s) * D_MODEL + h * DH + c0) = o;
    }
}

// -------------------------------------------------------------------------
// Kernel 3: output projection.  out[m][d] = sum_k attn[m][k] * WO[k][d]
// attn: [4096, 1024] row-major; WO viewed as [1024, 1024] row-major (he, d).
// -------------------------------------------------------------------------
__global__ __launch_bounds__(256) void out_proj_kernel(
    const float* __restrict__ A,
    const float* __restrict__ W,
    float* __restrict__ out)
{
    __shared__ float As[16][64];   // [k][m]
    __shared__ float Bs[16][68];   // [k][n], padded row stride 68 (16B-aligned, conflict-lite)

    const int m0  = blockIdx.x * 64;
    const int n0  = blockIdx.y * 64;
    const int tid = threadIdx.x;
    const int tx  = tid & 15;
    const int ty  = tid >> 4;

    const int lr = tid >> 2;
    const int lk = (tid & 3) * 4;
    const int bk = tid >> 4;          // 0..15 k-row for B load
    const int bn = (tid & 15) * 4;    // col*4 for B load

    float acc[4][4] = {};

    for (int k0 = 0; k0 < D_MODEL; k0 += 16) {
        float4 a = *(const float4*)(A + (size_t)(m0 + lr) * D_MODEL + k0 + lk);
        As[lk + 0][lr] = a.x; As[lk + 1][lr] = a.y;
        As[lk + 2][lr] = a.z; As[lk + 3][lr] = a.w;
        float4 b = *(const float4*)(W + (size_t)(k0 + bk) * D_MODEL + n0 + bn);
        *(float4*)&Bs[bk][bn] = b;
        __syncthreads();
        #pragma unroll
        for (int kk = 0; kk < 16; ++kk) {
            float av[4], bv[4];
            #pragma unroll
            for (int i = 0; i < 4; ++i) av[i] = As[kk][ty * 4 + i];
            #pragma unroll
            for (int j = 0; j < 4; ++j) bv[j] = Bs[kk][tx * 4 + j];
            #pragma unroll
            for (int i = 0; i < 4; ++i)
                #pragma unroll
                for (int j = 0; j < 4; ++j)
                    acc[i][j] += av[i] * bv[j];
        }
        __syncthreads();
    }

    #pragma unroll
    for (int i = 0; i < 4; ++i) {
        const int m = m0 + ty * 4 + i;
        float4 o = make_float4(acc[i][0], acc[i][1], acc[i][2], acc[i][3]);
        *(float4*)(out + (size_t)m * D_MODEL + n0 + tx * 4) = o;
    }
}

// -------------------------------------------------------------------------
extern "C" void kernel_launch(void* const* d_in, const int* in_sizes, int n_in,
                              void* d_out, int out_size, void* d_ws, size_t ws_size,
                              hipStream_t stream) {
    const float* X  = (const float*)d_in[0];   // residual [2,2048,1024]
    const float* WQ = (const float*)d_in[1];   // [16,64,1024]
    const float* WK = (const float*)d_in[2];
    const float* WV = (const float*)d_in[3];
    const float* WO = (const float*)d_in[4];
    float* out = (float*)d_out;                // [2,2048,1024]

    float* ws = (float*)d_ws;
    const size_t SZ = (size_t)BATCH * NH * S_LEN * DH;   // 4,194,304 floats
    float* qb   = ws;
    float* kb   = ws + SZ;
    float* vb   = ws + 2 * SZ;
    float* attn = ws + 3 * SZ;

    dim3 g1(4096 / 64, D_MODEL / 64, 3);
    qkv_kernel<<<g1, 256, 0, stream>>>(X, WQ, WK, WV, qb, kb, vb);

    dim3 g2(S_LEN / 64, BATCH * NH);
    flash_kernel<<<g2, 256, 0, stream>>>(qb, kb, vb, attn);

    dim3 g3(4096 / 64, D_MODEL / 64);
    out_proj_kernel<<<g3, 256, 0, stream>>>(attn, WO, out);
}

// Round 2
// 233.454 us; speedup vs baseline: 5.7461x; 5.7461x over previous
//
#include <hip/hip_runtime.h>
#include <math.h>

typedef unsigned short bf16;
typedef __attribute__((ext_vector_type(8))) short short8;
typedef __attribute__((ext_vector_type(4))) float f32x4;
typedef __attribute__((ext_vector_type(2))) float f32x2;

#define S_LEN 2048
#define NH    16
#define DH    64
#define DM    1024
#define BATCH 2

__device__ __forceinline__ bf16 f2bf(float f) {
    unsigned u = __float_as_uint(f);
    u += 0x7fffu + ((u >> 16) & 1u);          // RNE
    return (bf16)(u >> 16);
}

// async global->LDS, 16B per lane.  dest = ldsbase + lane*16 (wave-uniform base).
__device__ __forceinline__ void gload_lds16(const void* g, void* s) {
    __builtin_amdgcn_global_load_lds(
        (const __attribute__((address_space(1))) unsigned int*)g,
        (__attribute__((address_space(3))) unsigned int*)s, 16, 0, 0);
}

// -------------------------------------------------------------------------
// Convert fp32 inputs to bf16 staging buffers.
//  Xb  [4096][1024]        = residual
//  WQb [1024][1024]        = W_Q * 0.125   (scale folded)
//  WKb/WVb [1024][1024]
//  WOt [1024 d][1024 he]   = W_O transposed (k-contiguous for out-proj B)
// -------------------------------------------------------------------------
__global__ __launch_bounds__(256) void convert_kernel(
    const float* __restrict__ X,  const float* __restrict__ WQ,
    const float* __restrict__ WK, const float* __restrict__ WV,
    const float* __restrict__ WO,
    bf16* __restrict__ Xb, bf16* __restrict__ WQb, bf16* __restrict__ WKb,
    bf16* __restrict__ WVb, bf16* __restrict__ WOt)
{
    const int t = blockIdx.x * 256 + threadIdx.x;
    if (t < 1048576) {                         // X: 4M elems / 4
        float4 v = ((const float4*)X)[t];
        unsigned long long pk = (unsigned long long)f2bf(v.x)
            | ((unsigned long long)f2bf(v.y) << 16)
            | ((unsigned long long)f2bf(v.z) << 32)
            | ((unsigned long long)f2bf(v.w) << 48);
        *(unsigned long long*)(Xb + 4 * (size_t)t) = pk;
    } else if (t < 1310720) {                  // WQ (scaled)
        int i = t - 1048576;
        float4 v = ((const float4*)WQ)[i];
        unsigned long long pk = (unsigned long long)f2bf(v.x * 0.125f)
            | ((unsigned long long)f2bf(v.y * 0.125f) << 16)
            | ((unsigned long long)f2bf(v.z * 0.125f) << 32)
            | ((unsigned long long)f2bf(v.w * 0.125f) << 48);
        *(unsigned long long*)(WQb + 4 * (size_t)i) = pk;
    } else if (t < 1572864) {                  // WK
        int i = t - 1310720;
        float4 v = ((const float4*)WK)[i];
        unsigned long long pk = (unsigned long long)f2bf(v.x)
            | ((unsigned long long)f2bf(v.y) << 16)
            | ((unsigned long long)f2bf(v.z) << 32)
            | ((unsigned long long)f2bf(v.w) << 48);
        *(unsigned long long*)(WKb + 4 * (size_t)i) = pk;
    } else if (t < 1835008) {                  // WV
        int i = t - 1572864;
        float4 v = ((const float4*)WV)[i];
        unsigned long long pk = (unsigned long long)f2bf(v.x)
            | ((unsigned long long)f2bf(v.y) << 16)
            | ((unsigned long long)f2bf(v.z) << 32)
            | ((unsigned long long)f2bf(v.w) << 48);
        *(unsigned long long*)(WVb + 4 * (size_t)i) = pk;
    } else {                                   // WO transpose
        int i  = t - 1835008;                  // 256 threads per he-row
        int he = i >> 8, d0 = (i & 255) * 4;
        float4 v = *(const float4*)(WO + (size_t)he * DM + d0);
        WOt[(size_t)(d0 + 0) * DM + he] = f2bf(v.x);
        WOt[(size_t)(d0 + 1) * DM + he] = f2bf(v.y);
        WOt[(size_t)(d0 + 2) * DM + he] = f2bf(v.z);
        WOt[(size_t)(d0 + 3) * DM + he] = f2bf(v.w);
    }
}

// -------------------------------------------------------------------------
// QKV projection: C = Xb * W^T (both operands k-contiguous), 128x128 tile,
// BK=64, global_load_lds staging with XOR granule swizzle (g ^ (row&7)).
// Epilogue scatters bf16 to q/k [b,h,s,e] and V transposed [b,h,e,s].
// -------------------------------------------------------------------------
__global__ __launch_bounds__(256) void qkv_kernel(
    const bf16* __restrict__ Xb, const bf16* __restrict__ WQb,
    const bf16* __restrict__ WKb, const bf16* __restrict__ WVb,
    bf16* __restrict__ qb, bf16* __restrict__ kb, bf16* __restrict__ vt)
{
    __shared__ char lds[32768];
    char* As = lds;
    char* Bs = lds + 16384;

    const int z = blockIdx.z;
    const bf16* W = (z == 0) ? WQb : (z == 1) ? WKb : WVb;
    const int m0 = blockIdx.x * 128, n0 = blockIdx.y * 128;
    const int tid = threadIdx.x, wave = tid >> 6, lane = tid & 63;
    const int tx = lane & 15, quad = lane >> 4;
    const int wm = (wave >> 1) * 64, wn = (wave & 1) * 64;

    f32x4 acc[4][4] = {};

    for (int k0 = 0; k0 < DM; k0 += 64) {
        #pragma unroll
        for (int r = 0; r < 4; ++r) {
            int slot = r * 256 + tid;
            int row = slot >> 3, g = slot & 7, gl = g ^ (row & 7);
            gload_lds16(Xb + (size_t)(m0 + row) * DM + k0 + gl * 8,
                        As + r * 4096 + wave * 1024);
            gload_lds16(W + (size_t)(n0 + row) * DM + k0 + gl * 8,
                        Bs + r * 4096 + wave * 1024);
        }
        __syncthreads();
        #pragma unroll
        for (int ks = 0; ks < 2; ++ks) {
            const int swz = ((ks * 4 + quad) ^ (tx & 7)) * 16;
            short8 af[4], bfr[4];
            #pragma unroll
            for (int mt = 0; mt < 4; ++mt)
                af[mt] = *(const short8*)(As + (wm + mt * 16 + tx) * 128 + swz);
            #pragma unroll
            for (int nt = 0; nt < 4; ++nt)
                bfr[nt] = *(const short8*)(Bs + (wn + nt * 16 + tx) * 128 + swz);
            #pragma unroll
            for (int mt = 0; mt < 4; ++mt)
                #pragma unroll
                for (int nt = 0; nt < 4; ++nt)
                    acc[mt][nt] = __builtin_amdgcn_mfma_f32_16x16x32_bf16(
                        af[mt], bfr[nt], acc[mt][nt], 0, 0, 0);
        }
        __syncthreads();
    }

    #pragma unroll
    for (int mt = 0; mt < 4; ++mt)
        #pragma unroll
        for (int nt = 0; nt < 4; ++nt)
            #pragma unroll
            for (int r = 0; r < 4; ++r) {
                int mG = m0 + wm + mt * 16 + quad * 4 + r;   // token row
                int nG = n0 + wn + nt * 16 + tx;             // h*64+e
                int b = mG >> 11, s = mG & 2047, h = nG >> 6, e = nG & 63;
                bf16 v = f2bf(acc[mt][nt][r]);
                if (z == 0)
                    qb[((size_t)(b * NH + h) * S_LEN + s) * DH + e] = v;
                else if (z == 1)
                    kb[((size_t)(b * NH + h) * S_LEN + s) * DH + e] = v;
                else
                    vt[((size_t)(b * NH + h) * DH + e) * S_LEN + s] = v;
            }
}

// -------------------------------------------------------------------------
// Flash attention, bf16 MFMA.  Block = 4 waves, Q-tile 64 (16 q/wave),
// K-tile 64.  Computes S^T[k][q] (softmax reduction = 2 shuffles, O rescale
// in-lane), P^T round-trips a per-wave swizzled LDS strip, PV uses
// pre-transposed V.  O^T un-transposed via LDS in epilogue, written bf16.
// -------------------------------------------------------------------------
__global__ __launch_bounds__(256) void flash_kernel(
    const bf16* __restrict__ qb, const bf16* __restrict__ kb,
    const bf16* __restrict__ vtb, bf16* __restrict__ attn)
{
    __shared__ char lds[32768];
    char* Qs  = lds;
    char* Ks  = lds + 8192;
    char* Vts = lds + 16384;
    char* Pts = lds + 24576;

    const int qt = blockIdx.x, bh = blockIdx.y;
    const int tid = threadIdx.x, wave = tid >> 6, lane = tid & 63;
    const int tx = lane & 15, quad = lane >> 4;

    const bf16* Qg = qb + (size_t)bh * S_LEN * DH + (size_t)qt * 64 * DH;
    const bf16* Kg = kb + (size_t)bh * S_LEN * DH;
    const bf16* Vg = vtb + (size_t)bh * DH * S_LEN;

    // stage Q tile (8KB)
    #pragma unroll
    for (int r = 0; r < 2; ++r) {
        int slot = r * 256 + tid;
        int row = slot >> 3, g = slot & 7, gl = g ^ (row & 7);
        gload_lds16(Qg + (size_t)row * DH + gl * 8, Qs + r * 4096 + wave * 1024);
    }
    __syncthreads();

    short8 bq[2];
    #pragma unroll
    for (int es = 0; es < 2; ++es)
        bq[es] = *(const short8*)(Qs + (wave * 16 + tx) * 128 +
                                  (((es * 4 + quad) ^ (tx & 7)) * 16));

    f32x4 oacc[4] = {};
    float m_cur = -1e30f, l_cur = 0.0f;
    const int qglob = qt * 64 + wave * 16 + tx;

    for (int kt64 = 0; kt64 <= qt; ++kt64) {
        #pragma unroll
        for (int r = 0; r < 2; ++r) {
            int slot = r * 256 + tid;
            int row = slot >> 3, g = slot & 7, gl = g ^ (row & 7);
            gload_lds16(Kg + (size_t)(kt64 * 64 + row) * DH + gl * 8,
                        Ks + r * 4096 + wave * 1024);
            gload_lds16(Vg + (size_t)row * S_LEN + kt64 * 64 + gl * 8,
                        Vts + r * 4096 + wave * 1024);
        }
        __syncthreads();

        // S^T = K * Q^T   (D[m=k][n=q])
        f32x4 st[4] = {};
        #pragma unroll
        for (int kt = 0; kt < 4; ++kt) {
            #pragma unroll
            for (int es = 0; es < 2; ++es) {
                short8 ak = *(const short8*)(Ks + (kt * 16 + tx) * 128 +
                                             (((es * 4 + quad) ^ (tx & 7)) * 16));
                st[kt] = __builtin_amdgcn_mfma_f32_16x16x32_bf16(ak, bq[es], st[kt], 0, 0, 0);
            }
        }

        if (kt64 == qt) {   // causal mask, diagonal tile only
            #pragma unroll
            for (int kt = 0; kt < 4; ++kt)
                #pragma unroll
                for (int r = 0; r < 4; ++r) {
                    int kg = kt64 * 64 + kt * 16 + quad * 4 + r;
                    if (kg > qglob) st[kt][r] = -1e30f;
                }
        }

        // online softmax over k for this lane's column q = tx
        float tmax = -1e30f;
        #pragma unroll
        for (int kt = 0; kt < 4; ++kt)
            #pragma unroll
            for (int r = 0; r < 4; ++r) tmax = fmaxf(tmax, st[kt][r]);
        tmax = fmaxf(tmax, __shfl_xor(tmax, 16));
        tmax = fmaxf(tmax, __shfl_xor(tmax, 32));
        float mnew  = fmaxf(m_cur, tmax);
        float alpha = __expf(m_cur - mnew);
        float rsum = 0.0f;
        #pragma unroll
        for (int kt = 0; kt < 4; ++kt)
            #pragma unroll
            for (int r = 0; r < 4; ++r) {
                float p = __expf(st[kt][r] - mnew);
                st[kt][r] = p;
                rsum += p;
            }
        rsum += __shfl_xor(rsum, 16);
        rsum += __shfl_xor(rsum, 32);
        l_cur = l_cur * alpha + rsum;
        m_cur = mnew;
        #pragma unroll
        for (int et = 0; et < 4; ++et) oacc[et] *= alpha;

        // write P^T strip (per-wave, XOR-swizzled rows of 64 k)
        char* Ptw = Pts + wave * 2048;
        #pragma unroll
        for (int kt = 0; kt < 4; ++kt)
            #pragma unroll
            for (int h2 = 0; h2 < 2; ++h2) {
                int kk = kt * 16 + quad * 4 + h2 * 2;
                unsigned pk = (unsigned)f2bf(st[kt][h2 * 2]) |
                              ((unsigned)f2bf(st[kt][h2 * 2 + 1]) << 16);
                *(unsigned*)(Ptw + tx * 128 + (((kk >> 3) ^ (tx & 7)) * 16) +
                             (kk & 7) * 2) = pk;
            }
        asm volatile("s_waitcnt lgkmcnt(0)" ::: "memory");

        // O^T += V^T * P   (D[m=e][n=q])
        #pragma unroll
        for (int ks = 0; ks < 2; ++ks) {
            short8 bp = *(const short8*)(Ptw + tx * 128 +
                                         (((ks * 4 + quad) ^ (tx & 7)) * 16));
            #pragma unroll
            for (int et = 0; et < 4; ++et) {
                short8 av = *(const short8*)(Vts + (et * 16 + tx) * 128 +
                                             (((ks * 4 + quad) ^ (tx & 7)) * 16));
                oacc[et] = __builtin_amdgcn_mfma_f32_16x16x32_bf16(av, bp, oacc[et], 0, 0, 0);
            }
        }
        __syncthreads();
    }

    // epilogue: un-transpose O via LDS (per-wave 16q x 68-dword rows), write bf16
    float inv = 1.0f / l_cur;
    float* Otw = (float*)lds + wave * 1088;
    #pragma unroll
    for (int et = 0; et < 4; ++et)
        #pragma unroll
        for (int h2 = 0; h2 < 2; ++h2) {
            f32x2 pr;
            pr.x = oacc[et][h2 * 2] * inv;
            pr.y = oacc[et][h2 * 2 + 1] * inv;
            *(f32x2*)(Otw + tx * 68 + et * 16 + quad * 4 + h2 * 2) = pr;
        }
    asm volatile("s_waitcnt lgkmcnt(0)" ::: "memory");

    const int b = bh >> 4, h = bh & 15;
    const int s = qt * 64 + wave * 16 + tx;
    bf16* op = attn + ((size_t)b * S_LEN + s) * DM + h * DH + quad * 16;
    #pragma unroll
    for (int u = 0; u < 2; ++u) {
        f32x4 x = *(const f32x4*)(Otw + tx * 68 + quad * 16 + u * 8);
        f32x4 y = *(const f32x4*)(Otw + tx * 68 + quad * 16 + u * 8 + 4);
        short8 o8;
        o8[0] = (short)f2bf(x[0]); o8[1] = (short)f2bf(x[1]);
        o8[2] = (short)f2bf(x[2]); o8[3] = (short)f2bf(x[3]);
        o8[4] = (short)f2bf(y[0]); o8[5] = (short)f2bf(y[1]);
        o8[6] = (short)f2bf(y[2]); o8[7] = (short)f2bf(y[3]);
        *(short8*)(op + u * 8) = o8;
    }
}

// -------------------------------------------------------------------------
// Output projection: out = attn(bf16) * WOt^T, fp32 output.  Same core.
// -------------------------------------------------------------------------
__global__ __launch_bounds__(256) void out_proj_kernel(
    const bf16* __restrict__ A, const bf16* __restrict__ Bt,
    float* __restrict__ out)
{
    __shared__ char lds[32768];
    char* As = lds;
    char* Bs = lds + 16384;

    const int m0 = blockIdx.x * 128, n0 = blockIdx.y * 128;
    const int tid = threadIdx.x, wave = tid >> 6, lane = tid & 63;
    const int tx = lane & 15, quad = lane >> 4;
    const int wm = (wave >> 1) * 64, wn = (wave & 1) * 64;

    f32x4 acc[4][4] = {};

    for (int k0 = 0; k0 < DM; k0 += 64) {
        #pragma unroll
        for (int r = 0; r < 4; ++r) {
            int slot = r * 256 + tid;
            int row = slot >> 3, g = slot & 7, gl = g ^ (row & 7);
            gload_lds16(A + (size_t)(m0 + row) * DM + k0 + gl * 8,
                        As + r * 4096 + wave * 1024);
            gload_lds16(Bt + (size_t)(n0 + row) * DM + k0 + gl * 8,
                        Bs + r * 4096 + wave * 1024);
        }
        __syncthreads();
        #pragma unroll
        for (int ks = 0; ks < 2; ++ks) {
            const int swz = ((ks * 4 + quad) ^ (tx & 7)) * 16;
            short8 af[4], bfr[4];
            #pragma unroll
            for (int mt = 0; mt < 4; ++mt)
                af[mt] = *(const short8*)(As + (wm + mt * 16 + tx) * 128 + swz);
            #pragma unroll
            for (int nt = 0; nt < 4; ++nt)
                bfr[nt] = *(const short8*)(Bs + (wn + nt * 16 + tx) * 128 + swz);
            #pragma unroll
            for (int mt = 0; mt < 4; ++mt)
                #pragma unroll
                for (int nt = 0; nt < 4; ++nt)
                    acc[mt][nt] = __builtin_amdgcn_mfma_f32_16x16x32_bf16(
                        af[mt], bfr[nt], acc[mt][nt], 0, 0, 0);
        }
        __syncthreads();
    }

    #pragma unroll
    for (int mt = 0; mt < 4; ++mt)
        #pragma unroll
        for (int nt = 0; nt < 4; ++nt)
            #pragma unroll
            for (int r = 0; r < 4; ++r) {
                int mG = m0 + wm + mt * 16 + quad * 4 + r;
                int nG = n0 + wn + nt * 16 + tx;
                out[(size_t)mG * DM + nG] = acc[mt][nt][r];
            }
}

// -------------------------------------------------------------------------
extern "C" void kernel_launch(void* const* d_in, const int* in_sizes, int n_in,
                              void* d_out, int out_size, void* d_ws, size_t ws_size,
                              hipStream_t stream) {
    const float* X  = (const float*)d_in[0];
    const float* WQ = (const float*)d_in[1];
    const float* WK = (const float*)d_in[2];
    const float* WV = (const float*)d_in[3];
    const float* WO = (const float*)d_in[4];
    float* out = (float*)d_out;

    char* ws = (char*)d_ws;
    bf16* Xb   = (bf16*)(ws);                          // 8 MB
    bf16* WQb  = (bf16*)(ws + (8u  << 20));            // 2 MB
    bf16* WKb  = (bf16*)(ws + (10u << 20));            // 2 MB
    bf16* WVb  = (bf16*)(ws + (12u << 20));            // 2 MB
    bf16* WOt  = (bf16*)(ws + (14u << 20));            // 2 MB
    bf16* qb   = (bf16*)(ws + (16u << 20));            // 8 MB
    bf16* kb   = (bf16*)(ws + (24u << 20));            // 8 MB
    bf16* vt   = (bf16*)(ws + (32u << 20));            // 8 MB
    bf16* attn = (bf16*)(ws + (40u << 20));            // 8 MB

    convert_kernel<<<8192, 256, 0, stream>>>(X, WQ, WK, WV, WO,
                                             Xb, WQb, WKb, WVb, WOt);
    qkv_kernel<<<dim3(32, 8, 3), 256, 0, stream>>>(Xb, WQb, WKb, WVb, qb, kb, vt);
    flash_kernel<<<dim3(32, 32), 256, 0, stream>>>(qb, kb, vt, attn);
    out_proj_kernel<<<dim3(32, 8), 256, 0, stream>>>(attn, WOt, out);
}

// Round 3
// 216.543 us; speedup vs baseline: 6.1949x; 1.0781x over previous
//
#include <hip/hip_runtime.h>
#include <math.h>

typedef unsigned short bf16;
typedef __attribute__((ext_vector_type(8))) short short8;
typedef __attribute__((ext_vector_type(4))) float f32x4;

#define S_LEN 2048
#define NH    16
#define DH    64
#define DM    1024
#define BATCH 2

__device__ __forceinline__ bf16 f2bf(float f) {
    unsigned u = __float_as_uint(f);
    u += 0x7fffu + ((u >> 16) & 1u);          // RNE
    return (bf16)(u >> 16);
}

// pack two floats to packed bf16x2, round-half-up (cheap: 2 adds + shr + and_or)
__device__ __forceinline__ unsigned pack2(float a, float b) {
    unsigned ua = __float_as_uint(a) + 0x8000u;
    unsigned ub = __float_as_uint(b) + 0x8000u;
    return (ua >> 16) | (ub & 0xFFFF0000u);
}

__device__ __forceinline__ float fast_exp2(float x) {
#if __has_builtin(__builtin_amdgcn_exp2f)
    return __builtin_amdgcn_exp2f(x);
#else
    return exp2f(x);
#endif
}

// async global->LDS, 16B per lane.  dest = wave-uniform base + lane*16.
__device__ __forceinline__ void gload_lds16(const void* g, void* s) {
    __builtin_amdgcn_global_load_lds(
        (const __attribute__((address_space(1))) unsigned int*)g,
        (__attribute__((address_space(3))) unsigned int*)s, 16, 0, 0);
}

// -------------------------------------------------------------------------
// Convert fp32 inputs to bf16.  W_Q folded scale = 0.125 * log2(e) so the
// flash softmax runs in the exp2 domain (native v_exp_f32).
// -------------------------------------------------------------------------
#define QSCALE 0.18033688011112042f

__global__ __launch_bounds__(256) void convert_kernel(
    const float* __restrict__ X,  const float* __restrict__ WQ,
    const float* __restrict__ WK, const float* __restrict__ WV,
    const float* __restrict__ WO,
    bf16* __restrict__ Xb, bf16* __restrict__ WQb, bf16* __restrict__ WKb,
    bf16* __restrict__ WVb, bf16* __restrict__ WOt)
{
    const int t = blockIdx.x * 256 + threadIdx.x;
    if (t < 1048576) {                         // X
        float4 v = ((const float4*)X)[t];
        unsigned long long pk = (unsigned long long)f2bf(v.x)
            | ((unsigned long long)f2bf(v.y) << 16)
            | ((unsigned long long)f2bf(v.z) << 32)
            | ((unsigned long long)f2bf(v.w) << 48);
        *(unsigned long long*)(Xb + 4 * (size_t)t) = pk;
    } else if (t < 1310720) {                  // WQ (scaled)
        int i = t - 1048576;
        float4 v = ((const float4*)WQ)[i];
        unsigned long long pk = (unsigned long long)f2bf(v.x * QSCALE)
            | ((unsigned long long)f2bf(v.y * QSCALE) << 16)
            | ((unsigned long long)f2bf(v.z * QSCALE) << 32)
            | ((unsigned long long)f2bf(v.w * QSCALE) << 48);
        *(unsigned long long*)(WQb + 4 * (size_t)i) = pk;
    } else if (t < 1572864) {                  // WK
        int i = t - 1310720;
        float4 v = ((const float4*)WK)[i];
        unsigned long long pk = (unsigned long long)f2bf(v.x)
            | ((unsigned long long)f2bf(v.y) << 16)
            | ((unsigned long long)f2bf(v.z) << 32)
            | ((unsigned long long)f2bf(v.w) << 48);
        *(unsigned long long*)(WKb + 4 * (size_t)i) = pk;
    } else if (t < 1835008) {                  // WV
        int i = t - 1572864;
        float4 v = ((const float4*)WV)[i];
        unsigned long long pk = (unsigned long long)f2bf(v.x)
            | ((unsigned long long)f2bf(v.y) << 16)
            | ((unsigned long long)f2bf(v.z) << 32)
            | ((unsigned long long)f2bf(v.w) << 48);
        *(unsigned long long*)(WVb + 4 * (size_t)i) = pk;
    } else {                                   // WO transpose -> [d][he]
        int i  = t - 1835008;
        int he = i >> 8, d0 = (i & 255) * 4;
        float4 v = *(const float4*)(WO + (size_t)he * DM + d0);
        WOt[(size_t)(d0 + 0) * DM + he] = f2bf(v.x);
        WOt[(size_t)(d0 + 1) * DM + he] = f2bf(v.y);
        WOt[(size_t)(d0 + 2) * DM + he] = f2bf(v.z);
        WOt[(size_t)(d0 + 3) * DM + he] = f2bf(v.w);
    }
}

// -------------------------------------------------------------------------
// Q/K projection: C = Xb * W^T, 128x128 tile, BK=64, global_load_lds with
// XOR granule swizzle.  Scatter bf16 to [b,h,s,e].
// -------------------------------------------------------------------------
__global__ __launch_bounds__(256) void qk_kernel(
    const bf16* __restrict__ Xb, const bf16* __restrict__ WQb,
    const bf16* __restrict__ WKb,
    bf16* __restrict__ qbuf, bf16* __restrict__ kbuf)
{
    __shared__ char lds[32768];
    char* As = lds;
    char* Bs = lds + 16384;

    const int z = blockIdx.z;
    const bf16* W = (z == 0) ? WQb : WKb;
    bf16* outb = (z == 0) ? qbuf : kbuf;
    const int m0 = blockIdx.x * 128, n0 = blockIdx.y * 128;
    const int tid = threadIdx.x, wave = tid >> 6, lane = tid & 63;
    const int tx = lane & 15, quad = lane >> 4;
    const int wm = (wave >> 1) * 64, wn = (wave & 1) * 64;

    f32x4 acc[4][4] = {};

    for (int k0 = 0; k0 < DM; k0 += 64) {
        #pragma unroll
        for (int r = 0; r < 4; ++r) {
            int slot = r * 256 + tid;
            int row = slot >> 3, g = slot & 7, gl = g ^ (row & 7);
            gload_lds16(Xb + (size_t)(m0 + row) * DM + k0 + gl * 8,
                        As + r * 4096 + wave * 1024);
            gload_lds16(W + (size_t)(n0 + row) * DM + k0 + gl * 8,
                        Bs + r * 4096 + wave * 1024);
        }
        __syncthreads();
        #pragma unroll
        for (int ks = 0; ks < 2; ++ks) {
            const int swz = ((ks * 4 + quad) ^ (tx & 7)) * 16;
            short8 af[4], bfr[4];
            #pragma unroll
            for (int mt = 0; mt < 4; ++mt)
                af[mt] = *(const short8*)(As + (wm + mt * 16 + tx) * 128 + swz);
            #pragma unroll
            for (int nt = 0; nt < 4; ++nt)
                bfr[nt] = *(const short8*)(Bs + (wn + nt * 16 + tx) * 128 + swz);
            #pragma unroll
            for (int mt = 0; mt < 4; ++mt)
                #pragma unroll
                for (int nt = 0; nt < 4; ++nt)
                    acc[mt][nt] = __builtin_amdgcn_mfma_f32_16x16x32_bf16(
                        af[mt], bfr[nt], acc[mt][nt], 0, 0, 0);
        }
        __syncthreads();
    }

    #pragma unroll
    for (int mt = 0; mt < 4; ++mt)
        #pragma unroll
        for (int nt = 0; nt < 4; ++nt)
            #pragma unroll
            for (int r = 0; r < 4; ++r) {
                int mG = m0 + wm + mt * 16 + quad * 4 + r;   // token row
                int nG = n0 + wn + nt * 16 + tx;             // h*64+e
                int b = mG >> 11, s = mG & 2047, h = nG >> 6, e = nG & 63;
                outb[((size_t)(b * NH + h) * S_LEN + s) * DH + e] =
                    f2bf(acc[mt][nt][r]);
            }
}

// -------------------------------------------------------------------------
// V^T projection with transposed roles: C[he][s] = W_V * X^T per batch.
// Both operands k(d)-contiguous; output rows are s-contiguous -> coalesced.
// vt layout: [b, h, e, s].
// -------------------------------------------------------------------------
__global__ __launch_bounds__(256) void vt_kernel(
    const bf16* __restrict__ Xb, const bf16* __restrict__ WVb,
    bf16* __restrict__ vt)
{
    __shared__ char lds[32768];
    char* As = lds;
    char* Bs = lds + 16384;

    const int m0 = blockIdx.x * 128;              // he
    const int n0 = blockIdx.y * 128;              // s within batch
    const int b  = blockIdx.z;
    const int tid = threadIdx.x, wave = tid >> 6, lane = tid & 63;
    const int tx = lane & 15, quad = lane >> 4;
    const int wm = (wave >> 1) * 64, wn = (wave & 1) * 64;

    const bf16* Xbatch = Xb + (size_t)b * S_LEN * DM;

    f32x4 acc[4][4] = {};

    for (int k0 = 0; k0 < DM; k0 += 64) {
        #pragma unroll
        for (int r = 0; r < 4; ++r) {
            int slot = r * 256 + tid;
            int row = slot >> 3, g = slot & 7, gl = g ^ (row & 7);
            gload_lds16(WVb + (size_t)(m0 + row) * DM + k0 + gl * 8,
                        As + r * 4096 + wave * 1024);
            gload_lds16(Xbatch + (size_t)(n0 + row) * DM + k0 + gl * 8,
                        Bs + r * 4096 + wave * 1024);
        }
        __syncthreads();
        #pragma unroll
        for (int ks = 0; ks < 2; ++ks) {
            const int swz = ((ks * 4 + quad) ^ (tx & 7)) * 16;
            short8 af[4], bfr[4];
            #pragma unroll
            for (int mt = 0; mt < 4; ++mt)
                af[mt] = *(const short8*)(As + (wm + mt * 16 + tx) * 128 + swz);
            #pragma unroll
            for (int nt = 0; nt < 4; ++nt)
                bfr[nt] = *(const short8*)(Bs + (wn + nt * 16 + tx) * 128 + swz);
            #pragma unroll
            for (int mt = 0; mt < 4; ++mt)
                #pragma unroll
                for (int nt = 0; nt < 4; ++nt)
                    acc[mt][nt] = __builtin_amdgcn_mfma_f32_16x16x32_bf16(
                        af[mt], bfr[nt], acc[mt][nt], 0, 0, 0);
        }
        __syncthreads();
    }

    #pragma unroll
    for (int mt = 0; mt < 4; ++mt)
        #pragma unroll
        for (int nt = 0; nt < 4; ++nt)
            #pragma unroll
            for (int r = 0; r < 4; ++r) {
                int he = m0 + wm + mt * 16 + quad * 4 + r;
                int s  = n0 + wn + nt * 16 + tx;
                vt[((size_t)b * DM + he) * S_LEN + s] = f2bf(acc[mt][nt][r]);
            }
}

// -------------------------------------------------------------------------
// Flash attention, bf16 MFMA.  Q-tile 128 (4 waves x 32 q), K-tile 64.
// S^T layout (softmax = in-lane + 2 shuffles), P^T per-wave LDS strip,
// V pre-transposed.  Balanced qb mapping: heavy blocks first, complementary
// pairing across the grid.  Scores are in the exp2 domain (scale folded).
// -------------------------------------------------------------------------
__global__ __launch_bounds__(256) void flash_kernel(
    const bf16* __restrict__ qbuf, const bf16* __restrict__ kbuf,
    const bf16* __restrict__ vtb, bf16* __restrict__ attn)
{
    __shared__ char lds[32768];
    char* Ks  = lds;                // 8 KB: 64 k-rows x 128 B
    char* Vts = lds + 8192;         // 8 KB: 64 e-rows x 128 B
    char* Pts = lds + 16384;        // 16 KB: per-wave 4 KB strip [32 q][128 B]

    const int i  = blockIdx.x;
    const int bh = i & 31;
    const int j  = i >> 5;
    const int qb = (i < 256) ? (15 - j) : (j - 8);   // heavy-first, paired
    const int tid = threadIdx.x, wave = tid >> 6, lane = tid & 63;
    const int tx = lane & 15, quad = lane >> 4;
    const int sw = tx & 7;

    const bf16* Qg = qbuf + (size_t)bh * S_LEN * DH + (size_t)qb * 128 * DH;
    const bf16* Kg = kbuf + (size_t)bh * S_LEN * DH;
    const bf16* Vg = vtb  + (size_t)bh * DH * S_LEN;

    // stage Q tile (16 KB, into Ks+Vts region) and pull fragments
    #pragma unroll
    for (int r = 0; r < 4; ++r) {
        int slot = r * 256 + tid;
        int row = slot >> 3, g = slot & 7, gl = g ^ (row & 7);
        gload_lds16(Qg + (size_t)row * DH + gl * 8, lds + r * 4096 + wave * 1024);
    }
    __syncthreads();

    short8 bq[2][2];
    #pragma unroll
    for (int g = 0; g < 2; ++g)
        #pragma unroll
        for (int es = 0; es < 2; ++es)
            bq[g][es] = *(const short8*)(lds + (wave * 32 + g * 16 + tx) * 128 +
                                         (((es * 4 + quad) ^ sw) * 16));
    __syncthreads();   // Q reads done before K/V staging overwrites

    f32x4 oacc[2][4] = {};
    float m_cur[2] = {-1e30f, -1e30f};
    float l_cur[2] = {0.0f, 0.0f};

    const int kmax  = 2 * qb + 1;
    const int wdiag = 2 * qb + (wave >> 1);          // wave's diagonal k-tile
    const int qg0   = qb * 128 + wave * 32 + tx;     // + g*16 per group

    char* Pw = Pts + wave * 4096;

    for (int kt64 = 0; kt64 <= kmax; ++kt64) {
        #pragma unroll
        for (int r = 0; r < 2; ++r) {
            int slot = r * 256 + tid;
            int row = slot >> 3, g = slot & 7, gl = g ^ (row & 7);
            gload_lds16(Kg + ((size_t)kt64 * 64 + row) * DH + gl * 8,
                        Ks + r * 4096 + wave * 1024);
            gload_lds16(Vg + (size_t)row * S_LEN + kt64 * 64 + gl * 8,
                        Vts + r * 4096 + wave * 1024);
        }
        __syncthreads();

        if (kt64 <= wdiag) {                         // wave-uniform skip
            // S^T = K * Q^T
            f32x4 st[2][4] = {};
            #pragma unroll
            for (int es = 0; es < 2; ++es) {
                #pragma unroll
                for (int kt = 0; kt < 4; ++kt) {
                    short8 ak = *(const short8*)(Ks + (kt * 16 + tx) * 128 +
                                                 (((es * 4 + quad) ^ sw) * 16));
                    #pragma unroll
                    for (int g = 0; g < 2; ++g)
                        st[g][kt] = __builtin_amdgcn_mfma_f32_16x16x32_bf16(
                            ak, bq[g][es], st[g][kt], 0, 0, 0);
                }
            }

            if (kt64 == wdiag) {                     // causal mask
                #pragma unroll
                for (int g = 0; g < 2; ++g)
                    #pragma unroll
                    for (int kt = 0; kt < 4; ++kt)
                        #pragma unroll
                        for (int r = 0; r < 4; ++r)
                            if (kt64 * 64 + kt * 16 + quad * 4 + r > qg0 + g * 16)
                                st[g][kt][r] = -1e30f;
            }

            #pragma unroll
            for (int g = 0; g < 2; ++g) {
                float tmax = -1e30f;
                #pragma unroll
                for (int kt = 0; kt < 4; ++kt)
                    #pragma unroll
                    for (int r = 0; r < 4; ++r)
                        tmax = fmaxf(tmax, st[g][kt][r]);
                tmax = fmaxf(tmax, __shfl_xor(tmax, 16));
                tmax = fmaxf(tmax, __shfl_xor(tmax, 32));
                float mnew = fmaxf(m_cur[g], tmax);
                float al = fast_exp2(m_cur[g] - mnew);
                m_cur[g] = mnew;
                float rs = 0.0f;
                #pragma unroll
                for (int kt = 0; kt < 4; ++kt)
                    #pragma unroll
                    for (int r = 0; r < 4; ++r) {
                        float p = fast_exp2(st[g][kt][r] - mnew);
                        st[g][kt][r] = p;
                        rs += p;
                    }
                rs += __shfl_xor(rs, 16);
                rs += __shfl_xor(rs, 32);
                l_cur[g] = l_cur[g] * al + rs;
                #pragma unroll
                for (int et = 0; et < 4; ++et) oacc[g][et] *= al;

                // write P^T strip: row q = g*16+tx, k granule swizzled
                #pragma unroll
                for (int kt = 0; kt < 4; ++kt) {
                    unsigned lo = pack2(st[g][kt][0], st[g][kt][1]);
                    unsigned hi = pack2(st[g][kt][2], st[g][kt][3]);
                    int kg = kt * 2 + (quad >> 1);
                    *(uint2*)(Pw + (g * 16 + tx) * 128 + ((kg ^ sw) * 16) +
                              (quad & 1) * 8) = make_uint2(lo, hi);
                }
            }
            asm volatile("s_waitcnt lgkmcnt(0)" ::: "memory");

            // O^T += V^T * P
            #pragma unroll
            for (int ks = 0; ks < 2; ++ks) {
                const int swz = ((ks * 4 + quad) ^ sw) * 16;
                short8 bp[2];
                #pragma unroll
                for (int g = 0; g < 2; ++g)
                    bp[g] = *(const short8*)(Pw + (g * 16 + tx) * 128 + swz);
                #pragma unroll
                for (int et = 0; et < 4; ++et) {
                    short8 av = *(const short8*)(Vts + (et * 16 + tx) * 128 + swz);
                    #pragma unroll
                    for (int g = 0; g < 2; ++g)
                        oacc[g][et] = __builtin_amdgcn_mfma_f32_16x16x32_bf16(
                            av, bp[g], oacc[g][et], 0, 0, 0);
                }
            }
        }
        __syncthreads();
    }

    // epilogue: bf16-pack O^T into the per-wave strip, un-transpose, store
    const int b = bh >> 4, h = bh & 15;
    #pragma unroll
    for (int g = 0; g < 2; ++g) {
        float inv = 1.0f / l_cur[g];
        #pragma unroll
        for (int et = 0; et < 4; ++et) {
            unsigned lo = pack2(oacc[g][et][0] * inv, oacc[g][et][1] * inv);
            unsigned hi = pack2(oacc[g][et][2] * inv, oacc[g][et][3] * inv);
            int eg = et * 2 + (quad >> 1);
            *(uint2*)(Pw + (g * 16 + tx) * 128 + ((eg ^ sw) * 16) +
                      (quad & 1) * 8) = make_uint2(lo, hi);
        }
    }
    asm volatile("s_waitcnt lgkmcnt(0)" ::: "memory");

    #pragma unroll
    for (int g = 0; g < 2; ++g) {
        const int s = qb * 128 + wave * 32 + g * 16 + tx;
        bf16* op = attn + ((size_t)b * S_LEN + s) * DM + h * DH;
        #pragma unroll
        for (int c2 = 0; c2 < 2; ++c2) {
            int c = quad + c2 * 4;
            short8 v = *(const short8*)(Pw + (g * 16 + tx) * 128 + ((c ^ sw) * 16));
            *(short8*)(op + c * 8) = v;
        }
    }
}

// -------------------------------------------------------------------------
// Output projection: out = attn(bf16) * WOt^T, fp32 output.
// -------------------------------------------------------------------------
__global__ __launch_bounds__(256) void out_proj_kernel(
    const bf16* __restrict__ A, const bf16* __restrict__ Bt,
    float* __restrict__ out)
{
    __shared__ char lds[32768];
    char* As = lds;
    char* Bs = lds + 16384;

    const int m0 = blockIdx.x * 128, n0 = blockIdx.y * 128;
    const int tid = threadIdx.x, wave = tid >> 6, lane = tid & 63;
    const int tx = lane & 15, quad = lane >> 4;
    const int wm = (wave >> 1) * 64, wn = (wave & 1) * 64;

    f32x4 acc[4][4] = {};

    for (int k0 = 0; k0 < DM; k0 += 64) {
        #pragma unroll
        for (int r = 0; r < 4; ++r) {
            int slot = r * 256 + tid;
            int row = slot >> 3, g = slot & 7, gl = g ^ (row & 7);
            gload_lds16(A + (size_t)(m0 + row) * DM + k0 + gl * 8,
                        As + r * 4096 + wave * 1024);
            gload_lds16(Bt + (size_t)(n0 + row) * DM + k0 + gl * 8,
                        Bs + r * 4096 + wave * 1024);
        }
        __syncthreads();
        #pragma unroll
        for (int ks = 0; ks < 2; ++ks) {
            const int swz = ((ks * 4 + quad) ^ (tx & 7)) * 16;
            short8 af[4], bfr[4];
            #pragma unroll
            for (int mt = 0; mt < 4; ++mt)
                af[mt] = *(const short8*)(As + (wm + mt * 16 + tx) * 128 + swz);
            #pragma unroll
            for (int nt = 0; nt < 4; ++nt)
                bfr[nt] = *(const short8*)(Bs + (wn + nt * 16 + tx) * 128 + swz);
            #pragma unroll
            for (int mt = 0; mt < 4; ++mt)
                #pragma unroll
                for (int nt = 0; nt < 4; ++nt)
                    acc[mt][nt] = __builtin_amdgcn_mfma_f32_16x16x32_bf16(
                        af[mt], bfr[nt], acc[mt][nt], 0, 0, 0);
        }
        __syncthreads();
    }

    #pragma unroll
    for (int mt = 0; mt < 4; ++mt)
        #pragma unroll
        for (int nt = 0; nt < 4; ++nt)
            #pragma unroll
            for (int r = 0; r < 4; ++r) {
                int mG = m0 + wm + mt * 16 + quad * 4 + r;
                int nG = n0 + wn + nt * 16 + tx;
                out[(size_t)mG * DM + nG] = acc[mt][nt][r];
            }
}

// -------------------------------------------------------------------------
extern "C" void kernel_launch(void* const* d_in, const int* in_sizes, int n_in,
                              void* d_out, int out_size, void* d_ws, size_t ws_size,
                              hipStream_t stream) {
    const float* X  = (const float*)d_in[0];
    const float* WQ = (const float*)d_in[1];
    const float* WK = (const float*)d_in[2];
    const float* WV = (const float*)d_in[3];
    const float* WO = (const float*)d_in[4];
    float* out = (float*)d_out;

    char* ws = (char*)d_ws;
    bf16* Xb   = (bf16*)(ws);                          // 8 MB
    bf16* WQb  = (bf16*)(ws + (8u  << 20));            // 2 MB
    bf16* WKb  = (bf16*)(ws + (10u << 20));            // 2 MB
    bf16* WVb  = (bf16*)(ws + (12u << 20));            // 2 MB
    bf16* WOt  = (bf16*)(ws + (14u << 20));            // 2 MB
    bf16* qbuf = (bf16*)(ws + (16u << 20));            // 8 MB
    bf16* kbuf = (bf16*)(ws + (24u << 20));            // 8 MB
    bf16* vt   = (bf16*)(ws + (32u << 20));            // 8 MB
    bf16* attn = (bf16*)(ws + (40u << 20));            // 8 MB

    convert_kernel<<<8192, 256, 0, stream>>>(X, WQ, WK, WV, WO,
                                             Xb, WQb, WKb, WVb, WOt);
    qk_kernel<<<dim3(32, 8, 2), 256, 0, stream>>>(Xb, WQb, WKb, qbuf, kbuf);
    vt_kernel<<<dim3(8, 16, 2), 256, 0, stream>>>(Xb, WVb, vt);
    flash_kernel<<<512, 256, 0, stream>>>(qbuf, kbuf, vt, attn);
    out_proj_kernel<<<dim3(32, 8), 256, 0, stream>>>(attn, WOt, out);
}

// Round 4
// 192.041 us; speedup vs baseline: 6.9853x; 1.1276x over previous
//
#include <hip/hip_runtime.h>
#include <math.h>

typedef unsigned short bf16;
typedef __attribute__((ext_vector_type(8))) short short8;
typedef __attribute__((ext_vector_type(4))) float f32x4;

#define S_LEN 2048
#define NH    16
#define DH    64
#define DM    1024
#define BATCH 2

__device__ __forceinline__ bf16 f2bf(float f) {
    unsigned u = __float_as_uint(f);
    u += 0x7fffu + ((u >> 16) & 1u);          // RNE
    return (bf16)(u >> 16);
}

// pack two floats to packed bf16x2 (round-half-up; cheap)
__device__ __forceinline__ unsigned pack2(float a, float b) {
    unsigned ua = __float_as_uint(a) + 0x8000u;
    unsigned ub = __float_as_uint(b) + 0x8000u;
    return (ua >> 16) | (ub & 0xFFFF0000u);
}

__device__ __forceinline__ float fast_exp2(float x) {
#if __has_builtin(__builtin_amdgcn_exp2f)
    return __builtin_amdgcn_exp2f(x);
#else
    return exp2f(x);
#endif
}

// async global->LDS, 16B per lane.  dest = wave-uniform base + lane*16.
__device__ __forceinline__ void gload_lds16(const void* g, void* s) {
    __builtin_amdgcn_global_load_lds(
        (const __attribute__((address_space(1))) unsigned int*)g,
        (__attribute__((address_space(3))) unsigned int*)s, 16, 0, 0);
}

// -------------------------------------------------------------------------
// Convert fp32 -> bf16.  W_Q scale folded = 0.125*log2(e) (exp2-domain
// softmax).  WO transposed via LDS tiles (coalesced 128B store segments).
// Grid: 7168 elementwise blocks + 256 WO-transpose tile blocks = 7424.
// -------------------------------------------------------------------------
#define QSCALE 0.18033688011112042f

__global__ __launch_bounds__(256) void convert_kernel(
    const float* __restrict__ X,  const float* __restrict__ WQ,
    const float* __restrict__ WK, const float* __restrict__ WV,
    const float* __restrict__ WO,
    bf16* __restrict__ Xb, bf16* __restrict__ WQb, bf16* __restrict__ WKb,
    bf16* __restrict__ WVb, bf16* __restrict__ WOt)
{
    __shared__ float T[64][65];
    const int blk = blockIdx.x;
    if (blk < 7168) {
        const int t = blk * 256 + threadIdx.x;
        if (t < 1048576) {                         // X
            float4 v = ((const float4*)X)[t];
            unsigned long long pk = (unsigned long long)f2bf(v.x)
                | ((unsigned long long)f2bf(v.y) << 16)
                | ((unsigned long long)f2bf(v.z) << 32)
                | ((unsigned long long)f2bf(v.w) << 48);
            *(unsigned long long*)(Xb + 4 * (size_t)t) = pk;
        } else if (t < 1310720) {                  // WQ (scaled)
            int i = t - 1048576;
            float4 v = ((const float4*)WQ)[i];
            unsigned long long pk = (unsigned long long)f2bf(v.x * QSCALE)
                | ((unsigned long long)f2bf(v.y * QSCALE) << 16)
                | ((unsigned long long)f2bf(v.z * QSCALE) << 32)
                | ((unsigned long long)f2bf(v.w * QSCALE) << 48);
            *(unsigned long long*)(WQb + 4 * (size_t)i) = pk;
        } else if (t < 1572864) {                  // WK
            int i = t - 1310720;
            float4 v = ((const float4*)WK)[i];
            unsigned long long pk = (unsigned long long)f2bf(v.x)
                | ((unsigned long long)f2bf(v.y) << 16)
                | ((unsigned long long)f2bf(v.z) << 32)
                | ((unsigned long long)f2bf(v.w) << 48);
            *(unsigned long long*)(WKb + 4 * (size_t)i) = pk;
        } else {                                   // WV
            int i = t - 1572864;
            float4 v = ((const float4*)WV)[i];
            unsigned long long pk = (unsigned long long)f2bf(v.x)
                | ((unsigned long long)f2bf(v.y) << 16)
                | ((unsigned long long)f2bf(v.z) << 32)
                | ((unsigned long long)f2bf(v.w) << 48);
            *(unsigned long long*)(WVb + 4 * (size_t)i) = pk;
        }
    } else {                                       // WO transpose tile 64x64
        const int tile = blk - 7168;               // 0..255
        const int he0 = (tile & 15) * 64, d0 = (tile >> 4) * 64;
        const int tid = threadIdx.x;
        const int row = tid >> 2, c0 = (tid & 3) * 16;
        #pragma unroll
        for (int u = 0; u < 4; ++u) {
            float4 v = *(const float4*)(WO + (size_t)(he0 + row) * DM + d0 + c0 + u * 4);
            T[row][c0 + u * 4 + 0] = v.x;
            T[row][c0 + u * 4 + 1] = v.y;
            T[row][c0 + u * 4 + 2] = v.z;
            T[row][c0 + u * 4 + 3] = v.w;
        }
        __syncthreads();
        // out[d0+row][he0 + c0..c0+16) = T[c0+j][row]
        bf16 tmp[16];
        #pragma unroll
        for (int j = 0; j < 16; ++j) tmp[j] = f2bf(T[c0 + j][row]);
        *(short8*)(WOt + (size_t)(d0 + row) * DM + he0 + c0)     = *(short8*)&tmp[0];
        *(short8*)(WOt + (size_t)(d0 + row) * DM + he0 + c0 + 8) = *(short8*)&tmp[8];
    }
}

// -------------------------------------------------------------------------
// Merged projections, one launch (768 blocks):
//  id<512 : Q/K  (mode=id&1): C = Xb * W^T, 128x128, scatter [b,h,s,e]
//  id>=512: V^T : C[he][s] = W_V * X^T per batch, output [b,h,e,s]
// -------------------------------------------------------------------------
__global__ __launch_bounds__(256) void proj_kernel(
    const bf16* __restrict__ Xb, const bf16* __restrict__ WQb,
    const bf16* __restrict__ WKb, const bf16* __restrict__ WVb,
    bf16* __restrict__ qbuf, bf16* __restrict__ kbuf, bf16* __restrict__ vt)
{
    __shared__ char lds[32768];
    char* As = lds;
    char* Bs = lds + 16384;

    const int id = blockIdx.x;
    const int tid = threadIdx.x, wave = tid >> 6, lane = tid & 63;
    const int tx = lane & 15, quad = lane >> 4;
    const int wm = (wave >> 1) * 64, wn = (wave & 1) * 64;

    int mode, m0, n0, bb = 0;
    const bf16 *Aop, *Bop;
    if (id < 512) {
        mode = id & 1;                    // 0=Q, 1=K
        int rem = id >> 1;
        m0 = (rem & 31) * 128;            // token
        n0 = (rem >> 5) * 128;            // he
        Aop = Xb + (size_t)m0 * DM;
        Bop = (mode ? WKb : WQb) + (size_t)n0 * DM;
    } else {
        mode = 2;
        int rem = id - 512;
        bb = rem & 1;
        rem >>= 1;
        m0 = (rem & 7) * 128;             // he
        n0 = (rem >> 3) * 128;            // s (within batch)
        Aop = WVb + (size_t)m0 * DM;
        Bop = Xb + ((size_t)bb * S_LEN + n0) * DM;
    }

    f32x4 acc[4][4] = {};

    for (int k0 = 0; k0 < DM; k0 += 64) {
        #pragma unroll
        for (int r = 0; r < 4; ++r) {
            int slot = r * 256 + tid;
            int row = slot >> 3, g = slot & 7, gl = g ^ (row & 7);
            gload_lds16(Aop + (size_t)row * DM + k0 + gl * 8,
                        As + r * 4096 + wave * 1024);
            gload_lds16(Bop + (size_t)row * DM + k0 + gl * 8,
                        Bs + r * 4096 + wave * 1024);
        }
        __syncthreads();
        #pragma unroll
        for (int ks = 0; ks < 2; ++ks) {
            const int swz = ((ks * 4 + quad) ^ (tx & 7)) * 16;
            short8 af[4], bfr[4];
            #pragma unroll
            for (int mt = 0; mt < 4; ++mt)
                af[mt] = *(const short8*)(As + (wm + mt * 16 + tx) * 128 + swz);
            #pragma unroll
            for (int nt = 0; nt < 4; ++nt)
                bfr[nt] = *(const short8*)(Bs + (wn + nt * 16 + tx) * 128 + swz);
            #pragma unroll
            for (int mt = 0; mt < 4; ++mt)
                #pragma unroll
                for (int nt = 0; nt < 4; ++nt)
                    acc[mt][nt] = __builtin_amdgcn_mfma_f32_16x16x32_bf16(
                        af[mt], bfr[nt], acc[mt][nt], 0, 0, 0);
        }
        __syncthreads();
    }

    if (mode < 2) {
        bf16* outb = mode ? kbuf : qbuf;
        #pragma unroll
        for (int mt = 0; mt < 4; ++mt)
            #pragma unroll
            for (int nt = 0; nt < 4; ++nt)
                #pragma unroll
                for (int r = 0; r < 4; ++r) {
                    int mG = m0 + wm + mt * 16 + quad * 4 + r;   // token
                    int nG = n0 + wn + nt * 16 + tx;             // h*64+e
                    int b = mG >> 11, s = mG & 2047, h = nG >> 6, e = nG & 63;
                    outb[((size_t)(b * NH + h) * S_LEN + s) * DH + e] =
                        f2bf(acc[mt][nt][r]);
                }
    } else {
        #pragma unroll
        for (int mt = 0; mt < 4; ++mt)
            #pragma unroll
            for (int nt = 0; nt < 4; ++nt)
                #pragma unroll
                for (int r = 0; r < 4; ++r) {
                    int he = m0 + wm + mt * 16 + quad * 4 + r;
                    int s  = n0 + wn + nt * 16 + tx;
                    vt[((size_t)bb * DM + he) * S_LEN + s] = f2bf(acc[mt][nt][r]);
                }
    }
}

// -------------------------------------------------------------------------
// Flash attention, bf16 MFMA, double-buffered K/V staging.
// Q-tile 128 (4 waves x 32 q), K-tile 64.  S^T layout, P^T per-wave strip,
// V pre-transposed.  LDS 48KB: K0,V0,K1,V1 (8KB each) + P strips (16KB).
// -------------------------------------------------------------------------
__global__ __launch_bounds__(256) void flash_kernel(
    const bf16* __restrict__ qbuf, const bf16* __restrict__ kbuf,
    const bf16* __restrict__ vtb, bf16* __restrict__ attn)
{
    __shared__ char lds[49152];
    char* Pts = lds + 32768;

    const int i  = blockIdx.x;
    const int bh = i & 31;
    const int j  = i >> 5;
    const int qb = (i < 256) ? (15 - j) : (j - 8);   // heavy-first, paired
    const int tid = threadIdx.x, wave = tid >> 6, lane = tid & 63;
    const int tx = lane & 15, quad = lane >> 4;
    const int sw = tx & 7;

    const bf16* Qg = qbuf + (size_t)bh * S_LEN * DH + (size_t)qb * 128 * DH;
    const bf16* Kg = kbuf + (size_t)bh * S_LEN * DH;
    const bf16* Vg = vtb  + (size_t)bh * DH * S_LEN;

    // stage Q tile (16 KB, into buffer-0 region), pull fragments
    #pragma unroll
    for (int r = 0; r < 4; ++r) {
        int slot = r * 256 + tid;
        int row = slot >> 3, g = slot & 7, gl = g ^ (row & 7);
        gload_lds16(Qg + (size_t)row * DH + gl * 8, lds + r * 4096 + wave * 1024);
    }
    __syncthreads();

    short8 bq[2][2];
    #pragma unroll
    for (int g = 0; g < 2; ++g)
        #pragma unroll
        for (int es = 0; es < 2; ++es)
            bq[g][es] = *(const short8*)(lds + (wave * 32 + g * 16 + tx) * 128 +
                                         (((es * 4 + quad) ^ sw) * 16));
    __syncthreads();   // Q reads done before staging overwrites

    f32x4 oacc[2][4] = {};
    float m_cur[2] = {-1e30f, -1e30f};
    float l_cur[2] = {0.0f, 0.0f};

    const int kmax  = 2 * qb + 1;
    const int wdiag = 2 * qb + (wave >> 1);
    const int qg0   = qb * 128 + wave * 32 + tx;

    char* Pw = Pts + wave * 4096;

    // stage helper pattern (inlined): rounds r=0..1 cover 64 rows
    {
        char* Kb = lds;            // buffer 0
        char* Vb = lds + 8192;
        #pragma unroll
        for (int r = 0; r < 2; ++r) {
            int slot = r * 256 + tid;
            int row = slot >> 3, g = slot & 7, gl = g ^ (row & 7);
            gload_lds16(Kg + ((size_t)0 * 64 + row) * DH + gl * 8,
                        Kb + r * 4096 + wave * 1024);
            gload_lds16(Vg + (size_t)row * S_LEN + 0 * 64 + gl * 8,
                        Vb + r * 4096 + wave * 1024);
        }
    }

    for (int kt64 = 0; kt64 <= kmax; ++kt64) {
        char* Kc = lds + (kt64 & 1) * 16384;
        char* Vc = Kc + 8192;
        __syncthreads();                       // current buffer ready

        if (kt64 < kmax) {                     // prefetch next tile
            char* Kn = lds + ((kt64 + 1) & 1) * 16384;
            char* Vn = Kn + 8192;
            #pragma unroll
            for (int r = 0; r < 2; ++r) {
                int slot = r * 256 + tid;
                int row = slot >> 3, g = slot & 7, gl = g ^ (row & 7);
                gload_lds16(Kg + ((size_t)(kt64 + 1) * 64 + row) * DH + gl * 8,
                            Kn + r * 4096 + wave * 1024);
                gload_lds16(Vg + (size_t)row * S_LEN + (kt64 + 1) * 64 + gl * 8,
                            Vn + r * 4096 + wave * 1024);
            }
        }

        if (kt64 <= wdiag) {                   // wave-uniform skip
            // S^T = K * Q^T
            f32x4 st[2][4] = {};
            #pragma unroll
            for (int es = 0; es < 2; ++es) {
                #pragma unroll
                for (int kt = 0; kt < 4; ++kt) {
                    short8 ak = *(const short8*)(Kc + (kt * 16 + tx) * 128 +
                                                 (((es * 4 + quad) ^ sw) * 16));
                    #pragma unroll
                    for (int g = 0; g < 2; ++g)
                        st[g][kt] = __builtin_amdgcn_mfma_f32_16x16x32_bf16(
                            ak, bq[g][es], st[g][kt], 0, 0, 0);
                }
            }

            if (kt64 == wdiag) {               // causal mask on diagonal tile
                #pragma unroll
                for (int g = 0; g < 2; ++g)
                    #pragma unroll
                    for (int kt = 0; kt < 4; ++kt)
                        #pragma unroll
                        for (int r = 0; r < 4; ++r)
                            if (kt64 * 64 + kt * 16 + quad * 4 + r > qg0 + g * 16)
                                st[g][kt][r] = -1e30f;
            }

            #pragma unroll
            for (int g = 0; g < 2; ++g) {
                float tmax = -1e30f;
                #pragma unroll
                for (int kt = 0; kt < 4; ++kt)
                    #pragma unroll
                    for (int r = 0; r < 4; ++r)
                        tmax = fmaxf(tmax, st[g][kt][r]);
                tmax = fmaxf(tmax, __shfl_xor(tmax, 16));
                tmax = fmaxf(tmax, __shfl_xor(tmax, 32));
                float mnew = fmaxf(m_cur[g], tmax);
                float al = fast_exp2(m_cur[g] - mnew);
                m_cur[g] = mnew;
                float rs = 0.0f;
                #pragma unroll
                for (int kt = 0; kt < 4; ++kt)
                    #pragma unroll
                    for (int r = 0; r < 4; ++r) {
                        float p = fast_exp2(st[g][kt][r] - mnew);
                        st[g][kt][r] = p;
                        rs += p;
                    }
                rs += __shfl_xor(rs, 16);
                rs += __shfl_xor(rs, 32);
                l_cur[g] = l_cur[g] * al + rs;
                #pragma unroll
                for (int et = 0; et < 4; ++et) oacc[g][et] *= al;

                // write P^T strip
                #pragma unroll
                for (int kt = 0; kt < 4; ++kt) {
                    unsigned lo = pack2(st[g][kt][0], st[g][kt][1]);
                    unsigned hi = pack2(st[g][kt][2], st[g][kt][3]);
                    int kg = kt * 2 + (quad >> 1);
                    *(uint2*)(Pw + (g * 16 + tx) * 128 + ((kg ^ sw) * 16) +
                              (quad & 1) * 8) = make_uint2(lo, hi);
                }
            }
            asm volatile("s_waitcnt lgkmcnt(0)" ::: "memory");

            // O^T += V^T * P
            #pragma unroll
            for (int ks = 0; ks < 2; ++ks) {
                const int swz = ((ks * 4 + quad) ^ sw) * 16;
                short8 bp[2];
                #pragma unroll
                for (int g = 0; g < 2; ++g)
                    bp[g] = *(const short8*)(Pw + (g * 16 + tx) * 128 + swz);
                #pragma unroll
                for (int et = 0; et < 4; ++et) {
                    short8 av = *(const short8*)(Vc + (et * 16 + tx) * 128 + swz);
                    #pragma unroll
                    for (int g = 0; g < 2; ++g)
                        oacc[g][et] = __builtin_amdgcn_mfma_f32_16x16x32_bf16(
                            av, bp[g], oacc[g][et], 0, 0, 0);
                }
            }
        }
    }

    // epilogue: bf16-pack O^T into per-wave strip, un-transpose, store
    const int b = bh >> 4, h = bh & 15;
    #pragma unroll
    for (int g = 0; g < 2; ++g) {
        float inv = 1.0f / l_cur[g];
        #pragma unroll
        for (int et = 0; et < 4; ++et) {
            unsigned lo = pack2(oacc[g][et][0] * inv, oacc[g][et][1] * inv);
            unsigned hi = pack2(oacc[g][et][2] * inv, oacc[g][et][3] * inv);
            int eg = et * 2 + (quad >> 1);
            *(uint2*)(Pw + (g * 16 + tx) * 128 + ((eg ^ sw) * 16) +
                      (quad & 1) * 8) = make_uint2(lo, hi);
        }
    }
    asm volatile("s_waitcnt lgkmcnt(0)" ::: "memory");

    #pragma unroll
    for (int g = 0; g < 2; ++g) {
        const int s = qb * 128 + wave * 32 + g * 16 + tx;
        bf16* op = attn + ((size_t)b * S_LEN + s) * DM + h * DH;
        #pragma unroll
        for (int c2 = 0; c2 < 2; ++c2) {
            int c = quad + c2 * 4;
            short8 v = *(const short8*)(Pw + (g * 16 + tx) * 128 + ((c ^ sw) * 16));
            *(short8*)(op + c * 8) = v;
        }
    }
}

// -------------------------------------------------------------------------
// Output projection: out = attn(bf16) * WOt^T, fp32 out.  128x64 tiles,
// 512 blocks, 24 KB LDS (A 16KB + B 8KB), wave tile 32x64.
// -------------------------------------------------------------------------
__global__ __launch_bounds__(256) void out_proj_kernel(
    const bf16* __restrict__ A, const bf16* __restrict__ Bt,
    float* __restrict__ out)
{
    __shared__ char lds[24576];
    char* As = lds;            // 128 rows x 128B
    char* Bs = lds + 16384;    // 64 rows x 128B

    const int m0 = blockIdx.x * 128, n0 = blockIdx.y * 64;
    const int tid = threadIdx.x, wave = tid >> 6, lane = tid & 63;
    const int tx = lane & 15, quad = lane >> 4;
    const int wm = wave * 32;

    f32x4 acc[2][4] = {};

    for (int k0 = 0; k0 < DM; k0 += 64) {
        #pragma unroll
        for (int r = 0; r < 4; ++r) {
            int slot = r * 256 + tid;
            int row = slot >> 3, g = slot & 7, gl = g ^ (row & 7);
            gload_lds16(A + (size_t)(m0 + row) * DM + k0 + gl * 8,
                        As + r * 4096 + wave * 1024);
        }
        #pragma unroll
        for (int r = 0; r < 2; ++r) {
            int slot = r * 256 + tid;
            int row = slot >> 3, g = slot & 7, gl = g ^ (row & 7);
            gload_lds16(Bt + (size_t)(n0 + row) * DM + k0 + gl * 8,
                        Bs + r * 4096 + wave * 1024);
        }
        __syncthreads();
        #pragma unroll
        for (int ks = 0; ks < 2; ++ks) {
            const int swz = ((ks * 4 + quad) ^ (tx & 7)) * 16;
            short8 af[2], bfr[4];
            #pragma unroll
            for (int mt = 0; mt < 2; ++mt)
                af[mt] = *(const short8*)(As + (wm + mt * 16 + tx) * 128 + swz);
            #pragma unroll
            for (int nt = 0; nt < 4; ++nt)
                bfr[nt] = *(const short8*)(Bs + (nt * 16 + tx) * 128 + swz);
            #pragma unroll
            for (int mt = 0; mt < 2; ++mt)
                #pragma unroll
                for (int nt = 0; nt < 4; ++nt)
                    acc[mt][nt] = __builtin_amdgcn_mfma_f32_16x16x32_bf16(
                        af[mt], bfr[nt], acc[mt][nt], 0, 0, 0);
        }
        __syncthreads();
    }

    #pragma unroll
    for (int mt = 0; mt < 2; ++mt)
        #pragma unroll
        for (int nt = 0; nt < 4; ++nt)
            #pragma unroll
            for (int r = 0; r < 4; ++r) {
                int mG = m0 + wm + mt * 16 + quad * 4 + r;
                int nG = n0 + nt * 16 + tx;
                out[(size_t)mG * DM + nG] = acc[mt][nt][r];
            }
}

// -------------------------------------------------------------------------
extern "C" void kernel_launch(void* const* d_in, const int* in_sizes, int n_in,
                              void* d_out, int out_size, void* d_ws, size_t ws_size,
                              hipStream_t stream) {
    const float* X  = (const float*)d_in[0];
    const float* WQ = (const float*)d_in[1];
    const float* WK = (const float*)d_in[2];
    const float* WV = (const float*)d_in[3];
    const float* WO = (const float*)d_in[4];
    float* out = (float*)d_out;

    char* ws = (char*)d_ws;
    bf16* Xb   = (bf16*)(ws);                          // 8 MB
    bf16* WQb  = (bf16*)(ws + (8u  << 20));            // 2 MB
    bf16* WKb  = (bf16*)(ws + (10u << 20));            // 2 MB
    bf16* WVb  = (bf16*)(ws + (12u << 20));            // 2 MB
    bf16* WOt  = (bf16*)(ws + (14u << 20));            // 2 MB
    bf16* qbuf = (bf16*)(ws + (16u << 20));            // 8 MB
    bf16* kbuf = (bf16*)(ws + (24u << 20));            // 8 MB
    bf16* vt   = (bf16*)(ws + (32u << 20));            // 8 MB
    bf16* attn = (bf16*)(ws + (40u << 20));            // 8 MB

    convert_kernel<<<7424, 256, 0, stream>>>(X, WQ, WK, WV, WO,
                                             Xb, WQb, WKb, WVb, WOt);
    proj_kernel<<<768, 256, 0, stream>>>(Xb, WQb, WKb, WVb, qbuf, kbuf, vt);
    flash_kernel<<<512, 256, 0, stream>>>(qbuf, kbuf, vt, attn);
    out_proj_kernel<<<dim3(32, 16), 256, 0, stream>>>(attn, WOt, out);
}

// Round 5
// 176.999 us; speedup vs baseline: 7.5789x; 1.0850x over previous
//
#include <hip/hip_runtime.h>
#include <math.h>

typedef unsigned short bf16;
typedef __attribute__((ext_vector_type(8))) short short8;
typedef __attribute__((ext_vector_type(4))) float f32x4;

#define S_LEN 2048
#define NH    16
#define DH    64
#define DM    1024
#define BATCH 2

__device__ __forceinline__ bf16 f2bf(float f) {
    unsigned u = __float_as_uint(f);
    u += 0x7fffu + ((u >> 16) & 1u);          // RNE
    return (bf16)(u >> 16);
}

// pack two floats to packed bf16x2 (round-half-up; cheap)
__device__ __forceinline__ unsigned pack2(float a, float b) {
    unsigned ua = __float_as_uint(a) + 0x8000u;
    unsigned ub = __float_as_uint(b) + 0x8000u;
    return (ua >> 16) | (ub & 0xFFFF0000u);
}

__device__ __forceinline__ float fast_exp2(float x) {
#if __has_builtin(__builtin_amdgcn_exp2f)
    return __builtin_amdgcn_exp2f(x);
#else
    return exp2f(x);
#endif
}

// async global->LDS, 16B per lane.  dest = wave-uniform base + lane*16.
__device__ __forceinline__ void gload_lds16(const void* g, void* s) {
    __builtin_amdgcn_global_load_lds(
        (const __attribute__((address_space(1))) unsigned int*)g,
        (__attribute__((address_space(3))) unsigned int*)s, 16, 0, 0);
}

// -------------------------------------------------------------------------
// Convert fp32 -> bf16.  W_Q scale folded = 0.125*log2(e) (exp2-domain
// softmax).  WO transposed via LDS tiles (coalesced 128B store segments).
// -------------------------------------------------------------------------
#define QSCALE 0.18033688011112042f

__global__ __launch_bounds__(256) void convert_kernel(
    const float* __restrict__ X,  const float* __restrict__ WQ,
    const float* __restrict__ WK, const float* __restrict__ WV,
    const float* __restrict__ WO,
    bf16* __restrict__ Xb, bf16* __restrict__ WQb, bf16* __restrict__ WKb,
    bf16* __restrict__ WVb, bf16* __restrict__ WOt)
{
    __shared__ float T[64][65];
    const int blk = blockIdx.x;
    if (blk < 7168) {
        const int t = blk * 256 + threadIdx.x;
        if (t < 1048576) {                         // X
            float4 v = ((const float4*)X)[t];
            unsigned long long pk = (unsigned long long)f2bf(v.x)
                | ((unsigned long long)f2bf(v.y) << 16)
                | ((unsigned long long)f2bf(v.z) << 32)
                | ((unsigned long long)f2bf(v.w) << 48);
            *(unsigned long long*)(Xb + 4 * (size_t)t) = pk;
        } else if (t < 1310720) {                  // WQ (scaled)
            int i = t - 1048576;
            float4 v = ((const float4*)WQ)[i];
            unsigned long long pk = (unsigned long long)f2bf(v.x * QSCALE)
                | ((unsigned long long)f2bf(v.y * QSCALE) << 16)
                | ((unsigned long long)f2bf(v.z * QSCALE) << 32)
                | ((unsigned long long)f2bf(v.w * QSCALE) << 48);
            *(unsigned long long*)(WQb + 4 * (size_t)i) = pk;
        } else if (t < 1572864) {                  // WK
            int i = t - 1310720;
            float4 v = ((const float4*)WK)[i];
            unsigned long long pk = (unsigned long long)f2bf(v.x)
                | ((unsigned long long)f2bf(v.y) << 16)
                | ((unsigned long long)f2bf(v.z) << 32)
                | ((unsigned long long)f2bf(v.w) << 48);
            *(unsigned long long*)(WKb + 4 * (size_t)i) = pk;
        } else {                                   // WV
            int i = t - 1572864;
            float4 v = ((const float4*)WV)[i];
            unsigned long long pk = (unsigned long long)f2bf(v.x)
                | ((unsigned long long)f2bf(v.y) << 16)
                | ((unsigned long long)f2bf(v.z) << 32)
                | ((unsigned long long)f2bf(v.w) << 48);
            *(unsigned long long*)(WVb + 4 * (size_t)i) = pk;
        }
    } else {                                       // WO transpose tile 64x64
        const int tile = blk - 7168;               // 0..255
        const int he0 = (tile & 15) * 64, d0 = (tile >> 4) * 64;
        const int tid = threadIdx.x;
        const int row = tid >> 2, c0 = (tid & 3) * 16;
        #pragma unroll
        for (int u = 0; u < 4; ++u) {
            float4 v = *(const float4*)(WO + (size_t)(he0 + row) * DM + d0 + c0 + u * 4);
            T[row][c0 + u * 4 + 0] = v.x;
            T[row][c0 + u * 4 + 1] = v.y;
            T[row][c0 + u * 4 + 2] = v.z;
            T[row][c0 + u * 4 + 3] = v.w;
        }
        __syncthreads();
        bf16 tmp[16];
        #pragma unroll
        for (int j = 0; j < 16; ++j) tmp[j] = f2bf(T[c0 + j][row]);
        *(short8*)(WOt + (size_t)(d0 + row) * DM + he0 + c0)     = *(short8*)&tmp[0];
        *(short8*)(WOt + (size_t)(d0 + row) * DM + he0 + c0 + 8) = *(short8*)&tmp[8];
    }
}

// -------------------------------------------------------------------------
// Merged projections, one launch (768 blocks):
//  id<512 : Q/K  (mode=id&1): C = Xb * W^T, 128x128, scatter [b,h,s,e]
//  id>=512: V^T : C[he][s] = W_V * X^T per batch, output [b,h,e,s]
// -------------------------------------------------------------------------
__global__ __launch_bounds__(256) void proj_kernel(
    const bf16* __restrict__ Xb, const bf16* __restrict__ WQb,
    const bf16* __restrict__ WKb, const bf16* __restrict__ WVb,
    bf16* __restrict__ qbuf, bf16* __restrict__ kbuf, bf16* __restrict__ vt)
{
    __shared__ char lds[32768];
    char* As = lds;
    char* Bs = lds + 16384;

    const int id = blockIdx.x;
    const int tid = threadIdx.x, wave = tid >> 6, lane = tid & 63;
    const int tx = lane & 15, quad = lane >> 4;
    const int wm = (wave >> 1) * 64, wn = (wave & 1) * 64;

    int mode, m0, n0, bb = 0;
    const bf16 *Aop, *Bop;
    if (id < 512) {
        mode = id & 1;                    // 0=Q, 1=K
        int rem = id >> 1;
        m0 = (rem & 31) * 128;            // token
        n0 = (rem >> 5) * 128;            // he
        Aop = Xb + (size_t)m0 * DM;
        Bop = (mode ? WKb : WQb) + (size_t)n0 * DM;
    } else {
        mode = 2;
        int rem = id - 512;
        bb = rem & 1;
        rem >>= 1;
        m0 = (rem & 7) * 128;             // he
        n0 = (rem >> 3) * 128;            // s (within batch)
        Aop = WVb + (size_t)m0 * DM;
        Bop = Xb + ((size_t)bb * S_LEN + n0) * DM;
    }

    f32x4 acc[4][4] = {};

    for (int k0 = 0; k0 < DM; k0 += 64) {
        #pragma unroll
        for (int r = 0; r < 4; ++r) {
            int slot = r * 256 + tid;
            int row = slot >> 3, g = slot & 7, gl = g ^ (row & 7);
            gload_lds16(Aop + (size_t)row * DM + k0 + gl * 8,
                        As + r * 4096 + wave * 1024);
            gload_lds16(Bop + (size_t)row * DM + k0 + gl * 8,
                        Bs + r * 4096 + wave * 1024);
        }
        __syncthreads();
        #pragma unroll
        for (int ks = 0; ks < 2; ++ks) {
            const int swz = ((ks * 4 + quad) ^ (tx & 7)) * 16;
            short8 af[4], bfr[4];
            #pragma unroll
            for (int mt = 0; mt < 4; ++mt)
                af[mt] = *(const short8*)(As + (wm + mt * 16 + tx) * 128 + swz);
            #pragma unroll
            for (int nt = 0; nt < 4; ++nt)
                bfr[nt] = *(const short8*)(Bs + (wn + nt * 16 + tx) * 128 + swz);
            #pragma unroll
            for (int mt = 0; mt < 4; ++mt)
                #pragma unroll
                for (int nt = 0; nt < 4; ++nt)
                    acc[mt][nt] = __builtin_amdgcn_mfma_f32_16x16x32_bf16(
                        af[mt], bfr[nt], acc[mt][nt], 0, 0, 0);
        }
        __syncthreads();
    }

    if (mode < 2) {
        bf16* outb = mode ? kbuf : qbuf;
        #pragma unroll
        for (int mt = 0; mt < 4; ++mt)
            #pragma unroll
            for (int nt = 0; nt < 4; ++nt)
                #pragma unroll
                for (int r = 0; r < 4; ++r) {
                    int mG = m0 + wm + mt * 16 + quad * 4 + r;   // token
                    int nG = n0 + wn + nt * 16 + tx;             // h*64+e
                    int b = mG >> 11, s = mG & 2047, h = nG >> 6, e = nG & 63;
                    outb[((size_t)(b * NH + h) * S_LEN + s) * DH + e] =
                        f2bf(acc[mt][nt][r]);
                }
    } else {
        #pragma unroll
        for (int mt = 0; mt < 4; ++mt)
            #pragma unroll
            for (int nt = 0; nt < 4; ++nt)
                #pragma unroll
                for (int r = 0; r < 4; ++r) {
                    int he = m0 + wm + mt * 16 + quad * 4 + r;
                    int s  = n0 + wn + nt * 16 + tx;
                    vt[((size_t)bb * DM + he) * S_LEN + s] = f2bf(acc[mt][nt][r]);
                }
    }
}

// -------------------------------------------------------------------------
// Flash attention, bf16 MFMA, double-buffered K/V staging.
// Q-tile 128 (4 waves x 32 q), K-tile 64.  S^T layout, FIXED-BASE exp2
// softmax (no online max: scores are bounded; softmax is shift-invariant,
// fp32 range covers it).  l accumulated per-lane, reduced once in epilogue.
// Q fragments loaded directly from global (no LDS staging).
// -------------------------------------------------------------------------
__global__ __launch_bounds__(256) void flash_kernel(
    const bf16* __restrict__ qbuf, const bf16* __restrict__ kbuf,
    const bf16* __restrict__ vtb, bf16* __restrict__ attn)
{
    __shared__ char lds[49152];
    char* Pts = lds + 32768;

    const int i  = blockIdx.x;
    const int bh = i & 31;
    const int j  = i >> 5;
    const int qb = (i < 256) ? (15 - j) : (j - 8);   // heavy-first, paired
    const int tid = threadIdx.x, wave = tid >> 6, lane = tid & 63;
    const int tx = lane & 15, quad = lane >> 4;
    const int sw = tx & 7;

    const bf16* Qg = qbuf + (size_t)bh * S_LEN * DH + (size_t)qb * 128 * DH;
    const bf16* Kg = kbuf + (size_t)bh * S_LEN * DH;
    const bf16* Vg = vtb  + (size_t)bh * DH * S_LEN;

    // Q fragments straight from global: B-frag = 16B contiguous e per lane
    short8 bq[2][2];
    #pragma unroll
    for (int g = 0; g < 2; ++g)
        #pragma unroll
        for (int es = 0; es < 2; ++es)
            bq[g][es] = *(const short8*)(Qg + (size_t)(wave * 32 + g * 16 + tx) * DH +
                                         (es * 4 + quad) * 8);

    f32x4 oacc[2][4] = {};
    float l_part[2] = {0.0f, 0.0f};

    const int kmax  = 2 * qb + 1;
    const int wdiag = 2 * qb + (wave >> 1);
    const int qg0   = qb * 128 + wave * 32 + tx;

    char* Pw = Pts + wave * 4096;

    // stage k-tile 0 into buffer 0
    {
        char* Kb = lds;
        char* Vb = lds + 8192;
        #pragma unroll
        for (int r = 0; r < 2; ++r) {
            int slot = r * 256 + tid;
            int row = slot >> 3, g = slot & 7, gl = g ^ (row & 7);
            gload_lds16(Kg + (size_t)row * DH + gl * 8, Kb + r * 4096 + wave * 1024);
            gload_lds16(Vg + (size_t)row * S_LEN + gl * 8, Vb + r * 4096 + wave * 1024);
        }
    }

    for (int kt64 = 0; kt64 <= kmax; ++kt64) {
        char* Kc = lds + (kt64 & 1) * 16384;
        char* Vc = Kc + 8192;
        __syncthreads();                       // current buffer ready

        if (kt64 < kmax) {                     // prefetch next tile
            char* Kn = lds + ((kt64 + 1) & 1) * 16384;
            char* Vn = Kn + 8192;
            #pragma unroll
            for (int r = 0; r < 2; ++r) {
                int slot = r * 256 + tid;
                int row = slot >> 3, g = slot & 7, gl = g ^ (row & 7);
                gload_lds16(Kg + ((size_t)(kt64 + 1) * 64 + row) * DH + gl * 8,
                            Kn + r * 4096 + wave * 1024);
                gload_lds16(Vg + (size_t)row * S_LEN + (kt64 + 1) * 64 + gl * 8,
                            Vn + r * 4096 + wave * 1024);
            }
        }

        if (kt64 <= wdiag) {                   // wave-uniform causal skip
            // S^T = K * Q^T
            f32x4 st[2][4] = {};
            #pragma unroll
            for (int es = 0; es < 2; ++es) {
                #pragma unroll
                for (int kt = 0; kt < 4; ++kt) {
                    short8 ak = *(const short8*)(Kc + (kt * 16 + tx) * 128 +
                                                 (((es * 4 + quad) ^ sw) * 16));
                    #pragma unroll
                    for (int g = 0; g < 2; ++g)
                        st[g][kt] = __builtin_amdgcn_mfma_f32_16x16x32_bf16(
                            ak, bq[g][es], st[g][kt], 0, 0, 0);
                }
            }

            if (kt64 == wdiag) {               // causal mask on diagonal tile
                #pragma unroll
                for (int g = 0; g < 2; ++g)
                    #pragma unroll
                    for (int kt = 0; kt < 4; ++kt)
                        #pragma unroll
                        for (int r = 0; r < 4; ++r)
                            if (kt64 * 64 + kt * 16 + quad * 4 + r > qg0 + g * 16)
                                st[g][kt][r] = -1e30f;
            }

            // fixed-base softmax: p = 2^s, accumulate l per-lane, pack P
            #pragma unroll
            for (int g = 0; g < 2; ++g) {
                float rs = 0.0f;
                #pragma unroll
                for (int kt = 0; kt < 4; ++kt) {
                    #pragma unroll
                    for (int r = 0; r < 4; ++r) {
                        float p = fast_exp2(st[g][kt][r]);
                        st[g][kt][r] = p;
                        rs += p;
                    }
                    unsigned lo = pack2(st[g][kt][0], st[g][kt][1]);
                    unsigned hi = pack2(st[g][kt][2], st[g][kt][3]);
                    int kg = kt * 2 + (quad >> 1);
                    *(uint2*)(Pw + (g * 16 + tx) * 128 + ((kg ^ sw) * 16) +
                              (quad & 1) * 8) = make_uint2(lo, hi);
                }
                l_part[g] += rs;
            }
            asm volatile("s_waitcnt lgkmcnt(0)" ::: "memory");

            // O^T += V^T * P
            #pragma unroll
            for (int ks = 0; ks < 2; ++ks) {
                const int swz = ((ks * 4 + quad) ^ sw) * 16;
                short8 bp[2];
                #pragma unroll
                for (int g = 0; g < 2; ++g)
                    bp[g] = *(const short8*)(Pw + (g * 16 + tx) * 128 + swz);
                #pragma unroll
                for (int et = 0; et < 4; ++et) {
                    short8 av = *(const short8*)(Vc + (et * 16 + tx) * 128 + swz);
                    #pragma unroll
                    for (int g = 0; g < 2; ++g)
                        oacc[g][et] = __builtin_amdgcn_mfma_f32_16x16x32_bf16(
                            av, bp[g], oacc[g][et], 0, 0, 0);
                }
            }
        }
    }

    // epilogue: reduce l across quads (same q), divide, pack, un-transpose
    const int b = bh >> 4, h = bh & 15;
    #pragma unroll
    for (int g = 0; g < 2; ++g) {
        float l = l_part[g];
        l += __shfl_xor(l, 16);
        l += __shfl_xor(l, 32);
        float inv = 1.0f / l;
        #pragma unroll
        for (int et = 0; et < 4; ++et) {
            unsigned lo = pack2(oacc[g][et][0] * inv, oacc[g][et][1] * inv);
            unsigned hi = pack2(oacc[g][et][2] * inv, oacc[g][et][3] * inv);
            int eg = et * 2 + (quad >> 1);
            *(uint2*)(Pw + (g * 16 + tx) * 128 + ((eg ^ sw) * 16) +
                      (quad & 1) * 8) = make_uint2(lo, hi);
        }
    }
    asm volatile("s_waitcnt lgkmcnt(0)" ::: "memory");

    #pragma unroll
    for (int g = 0; g < 2; ++g) {
        const int s = qb * 128 + wave * 32 + g * 16 + tx;
        bf16* op = attn + ((size_t)b * S_LEN + s) * DM + h * DH;
        #pragma unroll
        for (int c2 = 0; c2 < 2; ++c2) {
            int c = quad + c2 * 4;
            short8 v = *(const short8*)(Pw + (g * 16 + tx) * 128 + ((c ^ sw) * 16));
            *(short8*)(op + c * 8) = v;
        }
    }
}

// -------------------------------------------------------------------------
// Output projection: out = attn(bf16) * WOt^T, fp32 out.  128x64 tiles,
// 512 blocks, 24 KB LDS (A 16KB + B 8KB), wave tile 32x64.
// -------------------------------------------------------------------------
__global__ __launch_bounds__(256) void out_proj_kernel(
    const bf16* __restrict__ A, const bf16* __restrict__ Bt,
    float* __restrict__ out)
{
    __shared__ char lds[24576];
    char* As = lds;            // 128 rows x 128B
    char* Bs = lds + 16384;    // 64 rows x 128B

    const int m0 = blockIdx.x * 128, n0 = blockIdx.y * 64;
    const int tid = threadIdx.x, wave = tid >> 6, lane = tid & 63;
    const int tx = lane & 15, quad = lane >> 4;
    const int wm = wave * 32;

    f32x4 acc[2][4] = {};

    for (int k0 = 0; k0 < DM; k0 += 64) {
        #pragma unroll
        for (int r = 0; r < 4; ++r) {
            int slot = r * 256 + tid;
            int row = slot >> 3, g = slot & 7, gl = g ^ (row & 7);
            gload_lds16(A + (size_t)(m0 + row) * DM + k0 + gl * 8,
                        As + r * 4096 + wave * 1024);
        }
        #pragma unroll
        for (int r = 0; r < 2; ++r) {
            int slot = r * 256 + tid;
            int row = slot >> 3, g = slot & 7, gl = g ^ (row & 7);
            gload_lds16(Bt + (size_t)(n0 + row) * DM + k0 + gl * 8,
                        Bs + r * 4096 + wave * 1024);
        }
        __syncthreads();
        #pragma unroll
        for (int ks = 0; ks < 2; ++ks) {
            const int swz = ((ks * 4 + quad) ^ (tx & 7)) * 16;
            short8 af[2], bfr[4];
            #pragma unroll
            for (int mt = 0; mt < 2; ++mt)
                af[mt] = *(const short8*)(As + (wm + mt * 16 + tx) * 128 + swz);
            #pragma unroll
            for (int nt = 0; nt < 4; ++nt)
                bfr[nt] = *(const short8*)(Bs + (nt * 16 + tx) * 128 + swz);
            #pragma unroll
            for (int mt = 0; mt < 2; ++mt)
                #pragma unroll
                for (int nt = 0; nt < 4; ++nt)
                    acc[mt][nt] = __builtin_amdgcn_mfma_f32_16x16x32_bf16(
                        af[mt], bfr[nt], acc[mt][nt], 0, 0, 0);
        }
        __syncthreads();
    }

    #pragma unroll
    for (int mt = 0; mt < 2; ++mt)
        #pragma unroll
        for (int nt = 0; nt < 4; ++nt)
            #pragma unroll
            for (int r = 0; r < 4; ++r) {
                int mG = m0 + wm + mt * 16 + quad * 4 + r;
                int nG = n0 + nt * 16 + tx;
                out[(size_t)mG * DM + nG] = acc[mt][nt][r];
            }
}

// -------------------------------------------------------------------------
extern "C" void kernel_launch(void* const* d_in, const int* in_sizes, int n_in,
                              void* d_out, int out_size, void* d_ws, size_t ws_size,
                              hipStream_t stream) {
    const float* X  = (const float*)d_in[0];
    const float* WQ = (const float*)d_in[1];
    const float* WK = (const float*)d_in[2];
    const float* WV = (const float*)d_in[3];
    const float* WO = (const float*)d_in[4];
    float* out = (float*)d_out;

    char* ws = (char*)d_ws;
    bf16* Xb   = (bf16*)(ws);                          // 8 MB
    bf16* WQb  = (bf16*)(ws + (8u  << 20));            // 2 MB
    bf16* WKb  = (bf16*)(ws + (10u << 20));            // 2 MB
    bf16* WVb  = (bf16*)(ws + (12u << 20));            // 2 MB
    bf16* WOt  = (bf16*)(ws + (14u << 20));            // 2 MB
    bf16* qbuf = (bf16*)(ws + (16u << 20));            // 8 MB
    bf16* kbuf = (bf16*)(ws + (24u << 20));            // 8 MB
    bf16* vt   = (bf16*)(ws + (32u << 20));            // 8 MB
    bf16* attn = (bf16*)(ws + (40u << 20));            // 8 MB

    convert_kernel<<<7424, 256, 0, stream>>>(X, WQ, WK, WV, WO,
                                             Xb, WQb, WKb, WVb, WOt);
    proj_kernel<<<768, 256, 0, stream>>>(Xb, WQb, WKb, WVb, qbuf, kbuf, vt);
    flash_kernel<<<512, 256, 0, stream>>>(qbuf, kbuf, vt, attn);
    out_proj_kernel<<<dim3(32, 16), 256, 0, stream>>>(attn, WOt, out);
}

// Round 6
// 171.126 us; speedup vs baseline: 7.8390x; 1.0343x over previous
//
#include <hip/hip_runtime.h>
#include <math.h>

typedef unsigned short bf16;
typedef unsigned long long u64;
typedef __attribute__((ext_vector_type(8))) short short8;
typedef __attribute__((ext_vector_type(4))) float f32x4;

#define S_LEN 2048
#define NH    16
#define DH    64
#define DM    1024
#define BATCH 2

__device__ __forceinline__ bf16 f2bf(float f) {
    unsigned u = __float_as_uint(f);
    u += 0x7fffu + ((u >> 16) & 1u);          // RNE
    return (bf16)(u >> 16);
}

// pack two floats to packed bf16x2 (round-half-up; cheap)
__device__ __forceinline__ unsigned pack2(float a, float b) {
    unsigned ua = __float_as_uint(a) + 0x8000u;
    unsigned ub = __float_as_uint(b) + 0x8000u;
    return (ua >> 16) | (ub & 0xFFFF0000u);
}

__device__ __forceinline__ u64 pack4(f32x4 v) {
    return (u64)pack2(v[0], v[1]) | ((u64)pack2(v[2], v[3]) << 32);
}

__device__ __forceinline__ float fast_exp2(float x) {
#if __has_builtin(__builtin_amdgcn_exp2f)
    return __builtin_amdgcn_exp2f(x);
#else
    return exp2f(x);
#endif
}

// async global->LDS, 16B per lane.  dest = wave-uniform base + lane*16.
__device__ __forceinline__ void gload_lds16(const void* g, void* s) {
    __builtin_amdgcn_global_load_lds(
        (const __attribute__((address_space(1))) unsigned int*)g,
        (__attribute__((address_space(3))) unsigned int*)s, 16, 0, 0);
}

// -------------------------------------------------------------------------
// Convert fp32 -> bf16.  W_Q scale folded = 0.125*log2(e) (exp2-domain
// softmax).  WO transposed via LDS tiles (coalesced 128B store segments).
// -------------------------------------------------------------------------
#define QSCALE 0.18033688011112042f

__global__ __launch_bounds__(256) void convert_kernel(
    const float* __restrict__ X,  const float* __restrict__ WQ,
    const float* __restrict__ WK, const float* __restrict__ WV,
    const float* __restrict__ WO,
    bf16* __restrict__ Xb, bf16* __restrict__ WQb, bf16* __restrict__ WKb,
    bf16* __restrict__ WVb, bf16* __restrict__ WOt)
{
    __shared__ float T[64][65];
    const int blk = blockIdx.x;
    if (blk < 7168) {
        const int t = blk * 256 + threadIdx.x;
        if (t < 1048576) {                         // X
            float4 v = ((const float4*)X)[t];
            u64 pk = (u64)f2bf(v.x) | ((u64)f2bf(v.y) << 16)
                   | ((u64)f2bf(v.z) << 32) | ((u64)f2bf(v.w) << 48);
            *(u64*)(Xb + 4 * (size_t)t) = pk;
        } else if (t < 1310720) {                  // WQ (scaled)
            int i = t - 1048576;
            float4 v = ((const float4*)WQ)[i];
            u64 pk = (u64)f2bf(v.x * QSCALE) | ((u64)f2bf(v.y * QSCALE) << 16)
                   | ((u64)f2bf(v.z * QSCALE) << 32) | ((u64)f2bf(v.w * QSCALE) << 48);
            *(u64*)(WQb + 4 * (size_t)i) = pk;
        } else if (t < 1572864) {                  // WK
            int i = t - 1310720;
            float4 v = ((const float4*)WK)[i];
            u64 pk = (u64)f2bf(v.x) | ((u64)f2bf(v.y) << 16)
                   | ((u64)f2bf(v.z) << 32) | ((u64)f2bf(v.w) << 48);
            *(u64*)(WKb + 4 * (size_t)i) = pk;
        } else {                                   // WV
            int i = t - 1572864;
            float4 v = ((const float4*)WV)[i];
            u64 pk = (u64)f2bf(v.x) | ((u64)f2bf(v.y) << 16)
                   | ((u64)f2bf(v.z) << 32) | ((u64)f2bf(v.w) << 48);
            *(u64*)(WVb + 4 * (size_t)i) = pk;
        }
    } else {                                       // WO transpose tile 64x64
        const int tile = blk - 7168;               // 0..255
        const int he0 = (tile & 15) * 64, d0 = (tile >> 4) * 64;
        const int tid = threadIdx.x;
        const int row = tid >> 2, c0 = (tid & 3) * 16;
        #pragma unroll
        for (int u = 0; u < 4; ++u) {
            float4 v = *(const float4*)(WO + (size_t)(he0 + row) * DM + d0 + c0 + u * 4);
            T[row][c0 + u * 4 + 0] = v.x;
            T[row][c0 + u * 4 + 1] = v.y;
            T[row][c0 + u * 4 + 2] = v.z;
            T[row][c0 + u * 4 + 3] = v.w;
        }
        __syncthreads();
        bf16 tmp[16];
        #pragma unroll
        for (int j = 0; j < 16; ++j) tmp[j] = f2bf(T[c0 + j][row]);
        *(short8*)(WOt + (size_t)(d0 + row) * DM + he0 + c0)     = *(short8*)&tmp[0];
        *(short8*)(WOt + (size_t)(d0 + row) * DM + he0 + c0 + 8) = *(short8*)&tmp[8];
    }
}

// -------------------------------------------------------------------------
// Merged projections, double-buffered staging (64 KB LDS), one launch:
//  id<512 : Q/K (mode=id&1): A=W rows(he), B=X rows(token).
//           D: reg->he (packable), lane->token.  Scatter 8B to [b,h,s,e].
//  id>=512: V  : A=X rows(s), B=WV rows(he).
//           D: reg->s (packable), lane->he.  8B stores to vt [b,he,s].
// -------------------------------------------------------------------------
__global__ __launch_bounds__(256) void proj_kernel(
    const bf16* __restrict__ Xb, const bf16* __restrict__ WQb,
    const bf16* __restrict__ WKb, const bf16* __restrict__ WVb,
    bf16* __restrict__ qbuf, bf16* __restrict__ kbuf, bf16* __restrict__ vt)
{
    __shared__ char lds[65536];

    const int id = blockIdx.x;
    const int tid = threadIdx.x, wave = tid >> 6, lane = tid & 63;
    const int tx = lane & 15, quad = lane >> 4;
    const int wm = (wave >> 1) * 64, wn = (wave & 1) * 64;

    int mode, am0, bn0, bb = 0;
    const bf16 *Aop, *Bop;
    if (id < 512) {
        mode = id & 1;                    // 0=Q, 1=K
        int rem = id >> 1;
        bn0 = (rem & 31) * 128;           // token rows (B)
        am0 = (rem >> 5) * 128;           // he rows (A)
        Aop = (mode ? WKb : WQb) + (size_t)am0 * DM;
        Bop = Xb + (size_t)bn0 * DM;
    } else {
        mode = 2;
        int rem = id - 512;
        bb = rem & 1;
        rem >>= 1;
        bn0 = (rem & 7) * 128;            // he rows (B)
        am0 = (rem >> 3) * 128;           // s rows (A, within batch)
        Aop = Xb + ((size_t)bb * S_LEN + am0) * DM;
        Bop = WVb + (size_t)bn0 * DM;
    }

    f32x4 acc[4][4] = {};

    // prologue: stage k-slice 0 into buffer 0
    {
        char* As = lds;
        char* Bs = lds + 16384;
        #pragma unroll
        for (int r = 0; r < 4; ++r) {
            int slot = r * 256 + tid;
            int row = slot >> 3, g = slot & 7, gl = g ^ (row & 7);
            gload_lds16(Aop + (size_t)row * DM + gl * 8, As + r * 4096 + wave * 1024);
            gload_lds16(Bop + (size_t)row * DM + gl * 8, Bs + r * 4096 + wave * 1024);
        }
    }

    for (int kt = 0; kt < 16; ++kt) {
        char* As = lds + (kt & 1) * 32768;
        char* Bs = As + 16384;
        __syncthreads();                       // current buffer ready

        if (kt < 15) {                         // prefetch next k-slice
            char* An = lds + ((kt + 1) & 1) * 32768;
            char* Bn = An + 16384;
            const int k0 = (kt + 1) * 64;
            #pragma unroll
            for (int r = 0; r < 4; ++r) {
                int slot = r * 256 + tid;
                int row = slot >> 3, g = slot & 7, gl = g ^ (row & 7);
                gload_lds16(Aop + (size_t)row * DM + k0 + gl * 8,
                            An + r * 4096 + wave * 1024);
                gload_lds16(Bop + (size_t)row * DM + k0 + gl * 8,
                            Bn + r * 4096 + wave * 1024);
            }
        }

        #pragma unroll
        for (int ks = 0; ks < 2; ++ks) {
            const int swz = ((ks * 4 + quad) ^ (tx & 7)) * 16;
            short8 af[4], bfr[4];
            #pragma unroll
            for (int mt = 0; mt < 4; ++mt)
                af[mt] = *(const short8*)(As + (wm + mt * 16 + tx) * 128 + swz);
            #pragma unroll
            for (int nt = 0; nt < 4; ++nt)
                bfr[nt] = *(const short8*)(Bs + (wn + nt * 16 + tx) * 128 + swz);
            #pragma unroll
            for (int mt = 0; mt < 4; ++mt)
                #pragma unroll
                for (int nt = 0; nt < 4; ++nt)
                    acc[mt][nt] = __builtin_amdgcn_mfma_f32_16x16x32_bf16(
                        af[mt], bfr[nt], acc[mt][nt], 0, 0, 0);
        }
    }

    if (mode < 2) {
        bf16* outb = mode ? kbuf : qbuf;
        #pragma unroll
        for (int mt = 0; mt < 4; ++mt)
            #pragma unroll
            for (int nt = 0; nt < 4; ++nt) {
                int heG  = am0 + wm + mt * 16 + quad * 4;    // + r in reg
                int tokG = bn0 + wn + nt * 16 + tx;
                int b = tokG >> 11, s = tokG & 2047;
                int h = heG >> 6, e0 = heG & 63;
                *(u64*)(outb + ((size_t)(b * NH + h) * S_LEN + s) * DH + e0) =
                    pack4(acc[mt][nt]);
            }
    } else {
        #pragma unroll
        for (int mt = 0; mt < 4; ++mt)
            #pragma unroll
            for (int nt = 0; nt < 4; ++nt) {
                int sG  = am0 + wm + mt * 16 + quad * 4;     // + r in reg
                int heG = bn0 + wn + nt * 16 + tx;
                *(u64*)(vt + ((size_t)bb * DM + heG) * S_LEN + sG) =
                    pack4(acc[mt][nt]);
            }
    }
}

// -------------------------------------------------------------------------
// Flash attention, bf16 MFMA, double-buffered K/V staging.
// Q-tile 128 (4 waves x 32 q), K-tile 64.  S^T layout, FIXED-BASE exp2
// softmax (no online max: scores bounded; softmax shift-invariant).
// l accumulated per-lane, reduced once in epilogue.  Q direct from global.
// -------------------------------------------------------------------------
__global__ __launch_bounds__(256) void flash_kernel(
    const bf16* __restrict__ qbuf, const bf16* __restrict__ kbuf,
    const bf16* __restrict__ vtb, bf16* __restrict__ attn)
{
    __shared__ char lds[49152];
    char* Pts = lds + 32768;

    const int i  = blockIdx.x;
    const int bh = i & 31;
    const int j  = i >> 5;
    const int qb = (i < 256) ? (15 - j) : (j - 8);   // heavy-first, paired
    const int tid = threadIdx.x, wave = tid >> 6, lane = tid & 63;
    const int tx = lane & 15, quad = lane >> 4;
    const int sw = tx & 7;

    const bf16* Qg = qbuf + (size_t)bh * S_LEN * DH + (size_t)qb * 128 * DH;
    const bf16* Kg = kbuf + (size_t)bh * S_LEN * DH;
    const bf16* Vg = vtb  + (size_t)bh * DH * S_LEN;

    // Q fragments straight from global: B-frag = 16B contiguous e per lane
    short8 bq[2][2];
    #pragma unroll
    for (int g = 0; g < 2; ++g)
        #pragma unroll
        for (int es = 0; es < 2; ++es)
            bq[g][es] = *(const short8*)(Qg + (size_t)(wave * 32 + g * 16 + tx) * DH +
                                         (es * 4 + quad) * 8);

    f32x4 oacc[2][4] = {};
    float l_part[2] = {0.0f, 0.0f};

    const int kmax  = 2 * qb + 1;
    const int wdiag = 2 * qb + (wave >> 1);
    const int qg0   = qb * 128 + wave * 32 + tx;

    char* Pw = Pts + wave * 4096;

    // stage k-tile 0 into buffer 0
    {
        char* Kb = lds;
        char* Vb = lds + 8192;
        #pragma unroll
        for (int r = 0; r < 2; ++r) {
            int slot = r * 256 + tid;
            int row = slot >> 3, g = slot & 7, gl = g ^ (row & 7);
            gload_lds16(Kg + (size_t)row * DH + gl * 8, Kb + r * 4096 + wave * 1024);
            gload_lds16(Vg + (size_t)row * S_LEN + gl * 8, Vb + r * 4096 + wave * 1024);
        }
    }

    for (int kt64 = 0; kt64 <= kmax; ++kt64) {
        char* Kc = lds + (kt64 & 1) * 16384;
        char* Vc = Kc + 8192;
        __syncthreads();                       // current buffer ready

        if (kt64 < kmax) {                     // prefetch next tile
            char* Kn = lds + ((kt64 + 1) & 1) * 16384;
            char* Vn = Kn + 8192;
            #pragma unroll
            for (int r = 0; r < 2; ++r) {
                int slot = r * 256 + tid;
                int row = slot >> 3, g = slot & 7, gl = g ^ (row & 7);
                gload_lds16(Kg + ((size_t)(kt64 + 1) * 64 + row) * DH + gl * 8,
                            Kn + r * 4096 + wave * 1024);
                gload_lds16(Vg + (size_t)row * S_LEN + (kt64 + 1) * 64 + gl * 8,
                            Vn + r * 4096 + wave * 1024);
            }
        }

        if (kt64 <= wdiag) {                   // wave-uniform causal skip
            // S^T = K * Q^T
            f32x4 st[2][4] = {};
            #pragma unroll
            for (int es = 0; es < 2; ++es) {
                #pragma unroll
                for (int kt = 0; kt < 4; ++kt) {
                    short8 ak = *(const short8*)(Kc + (kt * 16 + tx) * 128 +
                                                 (((es * 4 + quad) ^ sw) * 16));
                    #pragma unroll
                    for (int g = 0; g < 2; ++g)
                        st[g][kt] = __builtin_amdgcn_mfma_f32_16x16x32_bf16(
                            ak, bq[g][es], st[g][kt], 0, 0, 0);
                }
            }

            if (kt64 == wdiag) {               // causal mask on diagonal tile
                #pragma unroll
                for (int g = 0; g < 2; ++g)
                    #pragma unroll
                    for (int kt = 0; kt < 4; ++kt)
                        #pragma unroll
                        for (int r = 0; r < 4; ++r)
                            if (kt64 * 64 + kt * 16 + quad * 4 + r > qg0 + g * 16)
                                st[g][kt][r] = -1e30f;
            }

            // fixed-base softmax: p = 2^s, accumulate l per-lane, pack P
            #pragma unroll
            for (int g = 0; g < 2; ++g) {
                float rs = 0.0f;
                #pragma unroll
                for (int kt = 0; kt < 4; ++kt) {
                    #pragma unroll
                    for (int r = 0; r < 4; ++r) {
                        float p = fast_exp2(st[g][kt][r]);
                        st[g][kt][r] = p;
                        rs += p;
                    }
                    unsigned lo = pack2(st[g][kt][0], st[g][kt][1]);
                    unsigned hi = pack2(st[g][kt][2], st[g][kt][3]);
                    int kg = kt * 2 + (quad >> 1);
                    *(uint2*)(Pw + (g * 16 + tx) * 128 + ((kg ^ sw) * 16) +
                              (quad & 1) * 8) = make_uint2(lo, hi);
                }
                l_part[g] += rs;
            }
            asm volatile("s_waitcnt lgkmcnt(0)" ::: "memory");

            // O^T += V^T * P
            #pragma unroll
            for (int ks = 0; ks < 2; ++ks) {
                const int swz = ((ks * 4 + quad) ^ sw) * 16;
                short8 bp[2];
                #pragma unroll
                for (int g = 0; g < 2; ++g)
                    bp[g] = *(const short8*)(Pw + (g * 16 + tx) * 128 + swz);
                #pragma unroll
                for (int et = 0; et < 4; ++et) {
                    short8 av = *(const short8*)(Vc + (et * 16 + tx) * 128 + swz);
                    #pragma unroll
                    for (int g = 0; g < 2; ++g)
                        oacc[g][et] = __builtin_amdgcn_mfma_f32_16x16x32_bf16(
                            av, bp[g], oacc[g][et], 0, 0, 0);
                }
            }
        }
    }

    // epilogue: reduce l across quads (same q), divide, pack, un-transpose
    const int b = bh >> 4, h = bh & 15;
    #pragma unroll
    for (int g = 0; g < 2; ++g) {
        float l = l_part[g];
        l += __shfl_xor(l, 16);
        l += __shfl_xor(l, 32);
        float inv = 1.0f / l;
        #pragma unroll
        for (int et = 0; et < 4; ++et) {
            unsigned lo = pack2(oacc[g][et][0] * inv, oacc[g][et][1] * inv);
            unsigned hi = pack2(oacc[g][et][2] * inv, oacc[g][et][3] * inv);
            int eg = et * 2 + (quad >> 1);
            *(uint2*)(Pw + (g * 16 + tx) * 128 + ((eg ^ sw) * 16) +
                      (quad & 1) * 8) = make_uint2(lo, hi);
        }
    }
    asm volatile("s_waitcnt lgkmcnt(0)" ::: "memory");

    #pragma unroll
    for (int g = 0; g < 2; ++g) {
        const int s = qb * 128 + wave * 32 + g * 16 + tx;
        bf16* op = attn + ((size_t)b * S_LEN + s) * DM + h * DH;
        #pragma unroll
        for (int c2 = 0; c2 < 2; ++c2) {
            int c = quad + c2 * 4;
            short8 v = *(const short8*)(Pw + (g * 16 + tx) * 128 + ((c ^ sw) * 16));
            *(short8*)(op + c * 8) = v;
        }
    }
}

// -------------------------------------------------------------------------
// Output projection: out = attn(bf16) * WOt^T, fp32 out.  128x64 tiles,
// 512 blocks, double-buffered (48 KB LDS), wave tile 32x64.
// -------------------------------------------------------------------------
__global__ __launch_bounds__(256) void out_proj_kernel(
    const bf16* __restrict__ A, const bf16* __restrict__ Bt,
    float* __restrict__ out)
{
    __shared__ char lds[49152];

    const int m0 = blockIdx.x * 128, n0 = blockIdx.y * 64;
    const int tid = threadIdx.x, wave = tid >> 6, lane = tid & 63;
    const int tx = lane & 15, quad = lane >> 4;
    const int wm = wave * 32;

    f32x4 acc[2][4] = {};

    // prologue: stage k-slice 0 into buffer 0
    {
        char* As = lds;
        char* Bs = lds + 16384;
        #pragma unroll
        for (int r = 0; r < 4; ++r) {
            int slot = r * 256 + tid;
            int row = slot >> 3, g = slot & 7, gl = g ^ (row & 7);
            gload_lds16(A + (size_t)(m0 + row) * DM + gl * 8,
                        As + r * 4096 + wave * 1024);
        }
        #pragma unroll
        for (int r = 0; r < 2; ++r) {
            int slot = r * 256 + tid;
            int row = slot >> 3, g = slot & 7, gl = g ^ (row & 7);
            gload_lds16(Bt + (size_t)(n0 + row) * DM + gl * 8,
                        Bs + r * 4096 + wave * 1024);
        }
    }

    for (int kt = 0; kt < 16; ++kt) {
        char* As = lds + (kt & 1) * 24576;
        char* Bs = As + 16384;
        __syncthreads();

        if (kt < 15) {
            char* An = lds + ((kt + 1) & 1) * 24576;
            char* Bn = An + 16384;
            const int k0 = (kt + 1) * 64;
            #pragma unroll
            for (int r = 0; r < 4; ++r) {
                int slot = r * 256 + tid;
                int row = slot >> 3, g = slot & 7, gl = g ^ (row & 7);
                gload_lds16(A + (size_t)(m0 + row) * DM + k0 + gl * 8,
                            An + r * 4096 + wave * 1024);
            }
            #pragma unroll
            for (int r = 0; r < 2; ++r) {
                int slot = r * 256 + tid;
                int row = slot >> 3, g = slot & 7, gl = g ^ (row & 7);
                gload_lds16(Bt + (size_t)(n0 + row) * DM + k0 + gl * 8,
                            Bn + r * 4096 + wave * 1024);
            }
        }

        #pragma unroll
        for (int ks = 0; ks < 2; ++ks) {
            const int swz = ((ks * 4 + quad) ^ (tx & 7)) * 16;
            short8 af[2], bfr[4];
            #pragma unroll
            for (int mt = 0; mt < 2; ++mt)
                af[mt] = *(const short8*)(As + (wm + mt * 16 + tx) * 128 + swz);
            #pragma unroll
            for (int nt = 0; nt < 4; ++nt)
                bfr[nt] = *(const short8*)(Bs + (nt * 16 + tx) * 128 + swz);
            #pragma unroll
            for (int mt = 0; mt < 2; ++mt)
                #pragma unroll
                for (int nt = 0; nt < 4; ++nt)
                    acc[mt][nt] = __builtin_amdgcn_mfma_f32_16x16x32_bf16(
                        af[mt], bfr[nt], acc[mt][nt], 0, 0, 0);
        }
    }

    #pragma unroll
    for (int mt = 0; mt < 2; ++mt)
        #pragma unroll
        for (int nt = 0; nt < 4; ++nt)
            #pragma unroll
            for (int r = 0; r < 4; ++r) {
                int mG = m0 + wm + mt * 16 + quad * 4 + r;
                int nG = n0 + nt * 16 + tx;
                out[(size_t)mG * DM + nG] = acc[mt][nt][r];
            }
}

// -------------------------------------------------------------------------
extern "C" void kernel_launch(void* const* d_in, const int* in_sizes, int n_in,
                              void* d_out, int out_size, void* d_ws, size_t ws_size,
                              hipStream_t stream) {
    const float* X  = (const float*)d_in[0];
    const float* WQ = (const float*)d_in[1];
    const float* WK = (const float*)d_in[2];
    const float* WV = (const float*)d_in[3];
    const float* WO = (const float*)d_in[4];
    float* out = (float*)d_out;

    char* ws = (char*)d_ws;
    bf16* Xb   = (bf16*)(ws);                          // 8 MB
    bf16* WQb  = (bf16*)(ws + (8u  << 20));            // 2 MB
    bf16* WKb  = (bf16*)(ws + (10u << 20));            // 2 MB
    bf16* WVb  = (bf16*)(ws + (12u << 20));            // 2 MB
    bf16* WOt  = (bf16*)(ws + (14u << 20));            // 2 MB
    bf16* qbuf = (bf16*)(ws + (16u << 20));            // 8 MB
    bf16* kbuf = (bf16*)(ws + (24u << 20));            // 8 MB
    bf16* vt   = (bf16*)(ws + (32u << 20));            // 8 MB
    bf16* attn = (bf16*)(ws + (40u << 20));            // 8 MB

    convert_kernel<<<7424, 256, 0, stream>>>(X, WQ, WK, WV, WO,
                                             Xb, WQb, WKb, WVb, WOt);
    proj_kernel<<<768, 256, 0, stream>>>(Xb, WQb, WKb, WVb, qbuf, kbuf, vt);
    flash_kernel<<<512, 256, 0, stream>>>(qbuf, kbuf, vt, attn);
    out_proj_kernel<<<dim3(32, 16), 256, 0, stream>>>(attn, WOt, out);
}

// Round 8
// 169.842 us; speedup vs baseline: 7.8982x; 1.0076x over previous
//
#include <hip/hip_runtime.h>
#include <math.h>

typedef unsigned short bf16;
typedef unsigned long long u64;
typedef __attribute__((ext_vector_type(8))) short short8;
typedef __attribute__((ext_vector_type(4))) short s16x4;
typedef __attribute__((ext_vector_type(4))) float f32x4;

#define S_LEN 2048
#define NH    16
#define DH    64
#define DM    1024
#define BATCH 2

__device__ __forceinline__ bf16 f2bf(float f) {
    unsigned u = __float_as_uint(f);
    u += 0x7fffu + ((u >> 16) & 1u);          // RNE
    return (bf16)(u >> 16);
}

// pack two floats to packed bf16x2 (round-half-up; cheap)
__device__ __forceinline__ unsigned pack2(float a, float b) {
    unsigned ua = __float_as_uint(a) + 0x8000u;
    unsigned ub = __float_as_uint(b) + 0x8000u;
    return (ua >> 16) | (ub & 0xFFFF0000u);
}

__device__ __forceinline__ u64 pack4(f32x4 v) {
    return (u64)pack2(v[0], v[1]) | ((u64)pack2(v[2], v[3]) << 32);
}

__device__ __forceinline__ s16x4 pack4s(f32x4 v) {
    union { uint2 u; s16x4 s; } cv;
    cv.u = make_uint2(pack2(v[0], v[1]), pack2(v[2], v[3]));
    return cv.s;
}

__device__ __forceinline__ float fast_exp2(float x) {
#if __has_builtin(__builtin_amdgcn_exp2f)
    return __builtin_amdgcn_exp2f(x);
#else
    return exp2f(x);
#endif
}

// async global->LDS, 16B per lane.  dest = wave-uniform base + lane*16.
__device__ __forceinline__ void gload_lds16(const void* g, void* s) {
    __builtin_amdgcn_global_load_lds(
        (const __attribute__((address_space(1))) unsigned int*)g,
        (__attribute__((address_space(3))) unsigned int*)s, 16, 0, 0);
}

// -------------------------------------------------------------------------
// Convert fp32 -> bf16.  W_Q scale folded = 0.125*log2(e) (exp2-domain
// softmax).  WO transposed via LDS tiles (coalesced 128B store segments).
// -------------------------------------------------------------------------
#define QSCALE 0.18033688011112042f

__global__ __launch_bounds__(256) void convert_kernel(
    const float* __restrict__ X,  const float* __restrict__ WQ,
    const float* __restrict__ WK, const float* __restrict__ WV,
    const float* __restrict__ WO,
    bf16* __restrict__ Xb, bf16* __restrict__ WQb, bf16* __restrict__ WKb,
    bf16* __restrict__ WVb, bf16* __restrict__ WOt)
{
    __shared__ float T[64][65];
    const int blk = blockIdx.x;
    if (blk < 7168) {
        const int t = blk * 256 + threadIdx.x;
        if (t < 1048576) {                         // X
            float4 v = ((const float4*)X)[t];
            u64 pk = (u64)f2bf(v.x) | ((u64)f2bf(v.y) << 16)
                   | ((u64)f2bf(v.z) << 32) | ((u64)f2bf(v.w) << 48);
            *(u64*)(Xb + 4 * (size_t)t) = pk;
        } else if (t < 1310720) {                  // WQ (scaled)
            int i = t - 1048576;
            float4 v = ((const float4*)WQ)[i];
            u64 pk = (u64)f2bf(v.x * QSCALE) | ((u64)f2bf(v.y * QSCALE) << 16)
                   | ((u64)f2bf(v.z * QSCALE) << 32) | ((u64)f2bf(v.w * QSCALE) << 48);
            *(u64*)(WQb + 4 * (size_t)i) = pk;
        } else if (t < 1572864) {                  // WK
            int i = t - 1310720;
            float4 v = ((const float4*)WK)[i];
            u64 pk = (u64)f2bf(v.x) | ((u64)f2bf(v.y) << 16)
                   | ((u64)f2bf(v.z) << 32) | ((u64)f2bf(v.w) << 48);
            *(u64*)(WKb + 4 * (size_t)i) = pk;
        } else {                                   // WV
            int i = t - 1572864;
            float4 v = ((const float4*)WV)[i];
            u64 pk = (u64)f2bf(v.x) | ((u64)f2bf(v.y) << 16)
                   | ((u64)f2bf(v.z) << 32) | ((u64)f2bf(v.w) << 48);
            *(u64*)(WVb + 4 * (size_t)i) = pk;
        }
    } else {                                       // WO transpose tile 64x64
        const int tile = blk - 7168;               // 0..255
        const int he0 = (tile & 15) * 64, d0 = (tile >> 4) * 64;
        const int tid = threadIdx.x;
        const int row = tid >> 2, c0 = (tid & 3) * 16;
        #pragma unroll
        for (int u = 0; u < 4; ++u) {
            float4 v = *(const float4*)(WO + (size_t)(he0 + row) * DM + d0 + c0 + u * 4);
            T[row][c0 + u * 4 + 0] = v.x;
            T[row][c0 + u * 4 + 1] = v.y;
            T[row][c0 + u * 4 + 2] = v.z;
            T[row][c0 + u * 4 + 3] = v.w;
        }
        __syncthreads();
        bf16 tmp[16];
        #pragma unroll
        for (int j = 0; j < 16; ++j) tmp[j] = f2bf(T[c0 + j][row]);
        *(short8*)(WOt + (size_t)(d0 + row) * DM + he0 + c0)     = *(short8*)&tmp[0];
        *(short8*)(WOt + (size_t)(d0 + row) * DM + he0 + c0 + 8) = *(short8*)&tmp[8];
    }
}

// -------------------------------------------------------------------------
// Merged projections, double-buffered staging (64 KB LDS), one launch:
//  id<512 : Q/K (mode=id&1): A=W rows(he), B=X rows(token).
//  id>=512: V  : A=X rows(s), B=WV rows(he).  8B packed stores everywhere.
// -------------------------------------------------------------------------
__global__ __launch_bounds__(256) void proj_kernel(
    const bf16* __restrict__ Xb, const bf16* __restrict__ WQb,
    const bf16* __restrict__ WKb, const bf16* __restrict__ WVb,
    bf16* __restrict__ qbuf, bf16* __restrict__ kbuf, bf16* __restrict__ vt)
{
    __shared__ char lds[65536];

    const int id = blockIdx.x;
    const int tid = threadIdx.x, wave = tid >> 6, lane = tid & 63;
    const int tx = lane & 15, quad = lane >> 4;
    const int wm = (wave >> 1) * 64, wn = (wave & 1) * 64;

    int mode, am0, bn0, bb = 0;
    const bf16 *Aop, *Bop;
    if (id < 512) {
        mode = id & 1;                    // 0=Q, 1=K
        int rem = id >> 1;
        bn0 = (rem & 31) * 128;           // token rows (B)
        am0 = (rem >> 5) * 128;           // he rows (A)
        Aop = (mode ? WKb : WQb) + (size_t)am0 * DM;
        Bop = Xb + (size_t)bn0 * DM;
    } else {
        mode = 2;
        int rem = id - 512;
        bb = rem & 1;
        rem >>= 1;
        bn0 = (rem & 7) * 128;            // he rows (B)
        am0 = (rem >> 3) * 128;           // s rows (A, within batch)
        Aop = Xb + ((size_t)bb * S_LEN + am0) * DM;
        Bop = WVb + (size_t)bn0 * DM;
    }

    f32x4 acc[4][4] = {};

    // prologue: stage k-slice 0 into buffer 0
    {
        char* As = lds;
        char* Bs = lds + 16384;
        #pragma unroll
        for (int r = 0; r < 4; ++r) {
            int slot = r * 256 + tid;
            int row = slot >> 3, g = slot & 7, gl = g ^ (row & 7);
            gload_lds16(Aop + (size_t)row * DM + gl * 8, As + r * 4096 + wave * 1024);
            gload_lds16(Bop + (size_t)row * DM + gl * 8, Bs + r * 4096 + wave * 1024);
        }
    }

    for (int kt = 0; kt < 16; ++kt) {
        char* As = lds + (kt & 1) * 32768;
        char* Bs = As + 16384;
        __syncthreads();                       // current buffer ready

        if (kt < 15) {                         // prefetch next k-slice
            char* An = lds + ((kt + 1) & 1) * 32768;
            char* Bn = An + 16384;
            const int k0 = (kt + 1) * 64;
            #pragma unroll
            for (int r = 0; r < 4; ++r) {
                int slot = r * 256 + tid;
                int row = slot >> 3, g = slot & 7, gl = g ^ (row & 7);
                gload_lds16(Aop + (size_t)row * DM + k0 + gl * 8,
                            An + r * 4096 + wave * 1024);
                gload_lds16(Bop + (size_t)row * DM + k0 + gl * 8,
                            Bn + r * 4096 + wave * 1024);
            }
        }

        #pragma unroll
        for (int ks = 0; ks < 2; ++ks) {
            const int swz = ((ks * 4 + quad) ^ (tx & 7)) * 16;
            short8 af[4], bfr[4];
            #pragma unroll
            for (int mt = 0; mt < 4; ++mt)
                af[mt] = *(const short8*)(As + (wm + mt * 16 + tx) * 128 + swz);
            #pragma unroll
            for (int nt = 0; nt < 4; ++nt)
                bfr[nt] = *(const short8*)(Bs + (wn + nt * 16 + tx) * 128 + swz);
            #pragma unroll
            for (int mt = 0; mt < 4; ++mt)
                #pragma unroll
                for (int nt = 0; nt < 4; ++nt)
                    acc[mt][nt] = __builtin_amdgcn_mfma_f32_16x16x32_bf16(
                        af[mt], bfr[nt], acc[mt][nt], 0, 0, 0);
        }
    }

    if (mode < 2) {
        bf16* outb = mode ? kbuf : qbuf;
        #pragma unroll
        for (int mt = 0; mt < 4; ++mt)
            #pragma unroll
            for (int nt = 0; nt < 4; ++nt) {
                int heG  = am0 + wm + mt * 16 + quad * 4;    // + r in reg
                int tokG = bn0 + wn + nt * 16 + tx;
                int b = tokG >> 11, s = tokG & 2047;
                int h = heG >> 6, e0 = heG & 63;
                *(u64*)(outb + ((size_t)(b * NH + h) * S_LEN + s) * DH + e0) =
                    pack4(acc[mt][nt]);
            }
    } else {
        #pragma unroll
        for (int mt = 0; mt < 4; ++mt)
            #pragma unroll
            for (int nt = 0; nt < 4; ++nt) {
                int sG  = am0 + wm + mt * 16 + quad * 4;     // + r in reg
                int heG = bn0 + wn + nt * 16 + tx;
                *(u64*)(vt + ((size_t)bb * DM + heG) * S_LEN + sG) =
                    pack4(acc[mt][nt]);
            }
    }
}

// -------------------------------------------------------------------------
// Flash attention.  Q-tile 128 (4 waves x 32 q), K-tile 64, dbuf K/V
// (32 KB LDS total).  S^T via 16x16x32 MFMA; fixed-base exp2 softmax;
// PV via CHAINED 16x16x16 MFMA: the S^T C-layout (row=k=quad*4+r, col=q=tx)
// is exactly the 16x16x16 B-operand layout (B[k=quad*4+i][n=tx]), so P
// feeds PV straight from registers -- no LDS roundtrip, no bank conflicts.
// V^T A-frags are ds_read_b64 (A[m=tx][k=quad*4+i]).
// Epilogue reuses buffer 0 (last compute tile is always buffer 1: kmax odd).
// -------------------------------------------------------------------------
__global__ __launch_bounds__(256) void flash_kernel(
    const bf16* __restrict__ qbuf, const bf16* __restrict__ kbuf,
    const bf16* __restrict__ vtb, bf16* __restrict__ attn)
{
    __shared__ char lds[32768];

    const int i  = blockIdx.x;
    const int bh = i & 31;
    const int j  = i >> 5;
    const int qb = (i < 256) ? (15 - j) : (j - 8);   // heavy-first, paired
    const int tid = threadIdx.x, wave = tid >> 6, lane = tid & 63;
    const int tx = lane & 15, quad = lane >> 4;
    const int sw = tx & 7;

    const bf16* Qg = qbuf + (size_t)bh * S_LEN * DH + (size_t)qb * 128 * DH;
    const bf16* Kg = kbuf + (size_t)bh * S_LEN * DH;
    const bf16* Vg = vtb  + (size_t)bh * DH * S_LEN;

    // Q fragments straight from global: B-frag = 16B contiguous e per lane
    short8 bq[2][2];
    #pragma unroll
    for (int g = 0; g < 2; ++g)
        #pragma unroll
        for (int es = 0; es < 2; ++es)
            bq[g][es] = *(const short8*)(Qg + (size_t)(wave * 32 + g * 16 + tx) * DH +
                                         (es * 4 + quad) * 8);

    f32x4 oacc[2][4] = {};
    float l_part[2] = {0.0f, 0.0f};

    const int kmax  = 2 * qb + 1;                    // always odd
    const int wdiag = 2 * qb + (wave >> 1);
    const int qg0   = qb * 128 + wave * 32 + tx;

    // stage k-tile 0 into buffer 0 (K: lds+0, V: lds+8192)
    #pragma unroll
    for (int r = 0; r < 2; ++r) {
        int slot = r * 256 + tid;
        int row = slot >> 3, g = slot & 7, gl = g ^ (row & 7);
        gload_lds16(Kg + (size_t)row * DH + gl * 8, lds + r * 4096 + wave * 1024);
        gload_lds16(Vg + (size_t)row * S_LEN + gl * 8,
                    lds + 8192 + r * 4096 + wave * 1024);
    }

    for (int kt64 = 0; kt64 <= kmax; ++kt64) {
        char* Kc = lds + (kt64 & 1) * 16384;
        char* Vc = Kc + 8192;
        __syncthreads();                       // current buffer ready

        if (kt64 < kmax) {                     // prefetch next tile
            char* Kn = lds + ((kt64 + 1) & 1) * 16384;
            char* Vn = Kn + 8192;
            #pragma unroll
            for (int r = 0; r < 2; ++r) {
                int slot = r * 256 + tid;
                int row = slot >> 3, g = slot & 7, gl = g ^ (row & 7);
                gload_lds16(Kg + ((size_t)(kt64 + 1) * 64 + row) * DH + gl * 8,
                            Kn + r * 4096 + wave * 1024);
                gload_lds16(Vg + (size_t)row * S_LEN + (kt64 + 1) * 64 + gl * 8,
                            Vn + r * 4096 + wave * 1024);
            }
        }

        if (kt64 <= wdiag) {                   // wave-uniform causal skip
            // S^T = K * Q^T   (D[m=k][n=q])
            f32x4 st[2][4] = {};
            #pragma unroll
            for (int es = 0; es < 2; ++es) {
                #pragma unroll
                for (int kt = 0; kt < 4; ++kt) {
                    short8 ak = *(const short8*)(Kc + (kt * 16 + tx) * 128 +
                                                 (((es * 4 + quad) ^ sw) * 16));
                    #pragma unroll
                    for (int g = 0; g < 2; ++g)
                        st[g][kt] = __builtin_amdgcn_mfma_f32_16x16x32_bf16(
                            ak, bq[g][es], st[g][kt], 0, 0, 0);
                }
            }

            if (kt64 == wdiag) {               // causal mask on diagonal tile
                #pragma unroll
                for (int g = 0; g < 2; ++g)
                    #pragma unroll
                    for (int kt = 0; kt < 4; ++kt)
                        #pragma unroll
                        for (int r = 0; r < 4; ++r)
                            if (kt64 * 64 + kt * 16 + quad * 4 + r > qg0 + g * 16)
                                st[g][kt][r] = -1e30f;
            }

            // fixed-base softmax: p = 2^s; pack P into 16x16x16 B-frags
            s16x4 pb[2][4];
            #pragma unroll
            for (int g = 0; g < 2; ++g) {
                float rs = 0.0f;
                #pragma unroll
                for (int kt = 0; kt < 4; ++kt) {
                    #pragma unroll
                    for (int r = 0; r < 4; ++r) {
                        float p = fast_exp2(st[g][kt][r]);
                        st[g][kt][r] = p;
                        rs += p;
                    }
                    pb[g][kt] = pack4s(st[g][kt]);
                }
                l_part[g] += rs;
            }

            // O^T += V^T * P, chained 16x16x16 MFMA (P from registers)
            #pragma unroll
            for (int kt = 0; kt < 4; ++kt) {
                #pragma unroll
                for (int et = 0; et < 4; ++et) {
                    s16x4 av = *(const s16x4*)(Vc + (et * 16 + tx) * 128 +
                                 (((kt * 2 + (quad >> 1)) ^ sw) * 16) + (quad & 1) * 8);
                    #pragma unroll
                    for (int g = 0; g < 2; ++g)
                        oacc[g][et] = __builtin_amdgcn_mfma_f32_16x16x16bf16_1k(
                            av, pb[g][kt], oacc[g][et], 0, 0, 0);
                }
            }
        }
    }

    // epilogue: reduce l across quads, divide, pack, un-transpose via LDS.
    // Strips live in buffer 0 (16 KB) -- safe: last compute used buffer 1.
    const int b = bh >> 4, h = bh & 15;
    char* Pw = lds + wave * 4096;
    #pragma unroll
    for (int g = 0; g < 2; ++g) {
        float l = l_part[g];
        l += __shfl_xor(l, 16);
        l += __shfl_xor(l, 32);
        float inv = 1.0f / l;
        #pragma unroll
        for (int et = 0; et < 4; ++et) {
            unsigned lo = pack2(oacc[g][et][0] * inv, oacc[g][et][1] * inv);
            unsigned hi = pack2(oacc[g][et][2] * inv, oacc[g][et][3] * inv);
            int eg = et * 2 + (quad >> 1);
            *(uint2*)(Pw + (g * 16 + tx) * 128 + ((eg ^ sw) * 16) +
                      (quad & 1) * 8) = make_uint2(lo, hi);
        }
    }
    asm volatile("s_waitcnt lgkmcnt(0)" ::: "memory");

    #pragma unroll
    for (int g = 0; g < 2; ++g) {
        const int s = qb * 128 + wave * 32 + g * 16 + tx;
        bf16* op = attn + ((size_t)b * S_LEN + s) * DM + h * DH;
        #pragma unroll
        for (int c2 = 0; c2 < 2; ++c2) {
            int c = quad + c2 * 4;
            short8 v = *(const short8*)(Pw + (g * 16 + tx) * 128 + ((c ^ sw) * 16));
            *(short8*)(op + c * 8) = v;
        }
    }
}

// -------------------------------------------------------------------------
// Output projection: out = attn(bf16) * WOt^T, fp32 out.  128x64 tiles,
// 512 blocks, double-buffered (48 KB LDS), wave tile 32x64.
// -------------------------------------------------------------------------
__global__ __launch_bounds__(256) void out_proj_kernel(
    const bf16* __restrict__ A, const bf16* __restrict__ Bt,
    float* __restrict__ out)
{
    __shared__ char lds[49152];

    const int m0 = blockIdx.x * 128, n0 = blockIdx.y * 64;
    const int tid = threadIdx.x, wave = tid >> 6, lane = tid & 63;
    const int tx = lane & 15, quad = lane >> 4;
    const int wm = wave * 32;

    f32x4 acc[2][4] = {};

    {
        char* As = lds;
        char* Bs = lds + 16384;
        #pragma unroll
        for (int r = 0; r < 4; ++r) {
            int slot = r * 256 + tid;
            int row = slot >> 3, g = slot & 7, gl = g ^ (row & 7);
            gload_lds16(A + (size_t)(m0 + row) * DM + gl * 8,
                        As + r * 4096 + wave * 1024);
        }
        #pragma unroll
        for (int r = 0; r < 2; ++r) {
            int slot = r * 256 + tid;
            int row = slot >> 3, g = slot & 7, gl = g ^ (row & 7);
            gload_lds16(Bt + (size_t)(n0 + row) * DM + gl * 8,
                        Bs + r * 4096 + wave * 1024);
        }
    }

    for (int kt = 0; kt < 16; ++kt) {
        char* As = lds + (kt & 1) * 24576;
        char* Bs = As + 16384;
        __syncthreads();

        if (kt < 15) {
            char* An = lds + ((kt + 1) & 1) * 24576;
            char* Bn = An + 16384;
            const int k0 = (kt + 1) * 64;
            #pragma unroll
            for (int r = 0; r < 4; ++r) {
                int slot = r * 256 + tid;
                int row = slot >> 3, g = slot & 7, gl = g ^ (row & 7);
                gload_lds16(A + (size_t)(m0 + row) * DM + k0 + gl * 8,
                            An + r * 4096 + wave * 1024);
            }
            #pragma unroll
            for (int r = 0; r < 2; ++r) {
                int slot = r * 256 + tid;
                int row = slot >> 3, g = slot & 7, gl = g ^ (row & 7);
                gload_lds16(Bt + (size_t)(n0 + row) * DM + k0 + gl * 8,
                            Bn + r * 4096 + wave * 1024);
            }
        }

        #pragma unroll
        for (int ks = 0; ks < 2; ++ks) {
            const int swz = ((ks * 4 + quad) ^ (tx & 7)) * 16;
            short8 af[2], bfr[4];
            #pragma unroll
            for (int mt = 0; mt < 2; ++mt)
                af[mt] = *(const short8*)(As + (wm + mt * 16 + tx) * 128 + swz);
            #pragma unroll
            for (int nt = 0; nt < 4; ++nt)
                bfr[nt] = *(const short8*)(Bs + (nt * 16 + tx) * 128 + swz);
            #pragma unroll
            for (int mt = 0; mt < 2; ++mt)
                #pragma unroll
                for (int nt = 0; nt < 4; ++nt)
                    acc[mt][nt] = __builtin_amdgcn_mfma_f32_16x16x32_bf16(
                        af[mt], bfr[nt], acc[mt][nt], 0, 0, 0);
        }
    }

    #pragma unroll
    for (int mt = 0; mt < 2; ++mt)
        #pragma unroll
        for (int nt = 0; nt < 4; ++nt)
            #pragma unroll
            for (int r = 0; r < 4; ++r) {
                int mG = m0 + wm + mt * 16 + quad * 4 + r;
                int nG = n0 + nt * 16 + tx;
                out[(size_t)mG * DM + nG] = acc[mt][nt][r];
            }
}

// -------------------------------------------------------------------------
extern "C" void kernel_launch(void* const* d_in, const int* in_sizes, int n_in,
                              void* d_out, int out_size, void* d_ws, size_t ws_size,
                              hipStream_t stream) {
    const float* X  = (const float*)d_in[0];
    const float* WQ = (const float*)d_in[1];
    const float* WK = (const float*)d_in[2];
    const float* WV = (const float*)d_in[3];
    const float* WO = (const float*)d_in[4];
    float* out = (float*)d_out;

    char* ws = (char*)d_ws;
    bf16* Xb   = (bf16*)(ws);                          // 8 MB
    bf16* WQb  = (bf16*)(ws + (8u  << 20));            // 2 MB
    bf16* WKb  = (bf16*)(ws + (10u << 20));            // 2 MB
    bf16* WVb  = (bf16*)(ws + (12u << 20));            // 2 MB
    bf16* WOt  = (bf16*)(ws + (14u << 20));            // 2 MB
    bf16* qbuf = (bf16*)(ws + (16u << 20));            // 8 MB
    bf16* kbuf = (bf16*)(ws + (24u << 20));            // 8 MB
    bf16* vt   = (bf16*)(ws + (32u << 20));            // 8 MB
    bf16* attn = (bf16*)(ws + (40u << 20));            // 8 MB

    convert_kernel<<<7424, 256, 0, stream>>>(X, WQ, WK, WV, WO,
                                             Xb, WQb, WKb, WVb, WOt);
    proj_kernel<<<768, 256, 0, stream>>>(Xb, WQb, WKb, WVb, qbuf, kbuf, vt);
    flash_kernel<<<512, 256, 0, stream>>>(qbuf, kbuf, vt, attn);
    out_proj_kernel<<<dim3(32, 16), 256, 0, stream>>>(attn, WOt, out);
}

// Round 9
// 160.904 us; speedup vs baseline: 8.3370x; 1.0555x over previous
//
#include <hip/hip_runtime.h>
#include <math.h>

typedef unsigned short bf16;
typedef unsigned long long u64;
typedef __attribute__((ext_vector_type(8))) short short8;
typedef __attribute__((ext_vector_type(4))) short s16x4;
typedef __attribute__((ext_vector_type(4))) float f32x4;

#define S_LEN 2048
#define NH    16
#define DH    64
#define DM    1024
#define BATCH 2

__device__ __forceinline__ bf16 f2bf(float f) {
    unsigned u = __float_as_uint(f);
    u += 0x7fffu + ((u >> 16) & 1u);          // RNE
    return (bf16)(u >> 16);
}

// pack two floats to packed bf16x2 (round-half-up; cheap)
__device__ __forceinline__ unsigned pack2(float a, float b) {
    unsigned ua = __float_as_uint(a) + 0x8000u;
    unsigned ub = __float_as_uint(b) + 0x8000u;
    return (ua >> 16) | (ub & 0xFFFF0000u);
}

__device__ __forceinline__ u64 pack4(f32x4 v) {
    return (u64)pack2(v[0], v[1]) | ((u64)pack2(v[2], v[3]) << 32);
}

__device__ __forceinline__ s16x4 pack4s(f32x4 v) {
    union { uint2 u; s16x4 s; } cv;
    cv.u = make_uint2(pack2(v[0], v[1]), pack2(v[2], v[3]));
    return cv.s;
}

__device__ __forceinline__ float fast_exp2(float x) {
#if __has_builtin(__builtin_amdgcn_exp2f)
    return __builtin_amdgcn_exp2f(x);
#else
    return exp2f(x);
#endif
}

// async global->LDS, 16B per lane.  dest = wave-uniform base + lane*16.
__device__ __forceinline__ void gload_lds16(const void* g, void* s) {
    __builtin_amdgcn_global_load_lds(
        (const __attribute__((address_space(1))) unsigned int*)g,
        (__attribute__((address_space(3))) unsigned int*)s, 16, 0, 0);
}

// -------------------------------------------------------------------------
// Convert fp32 -> bf16.  W_Q scale folded = 0.125*log2(e) (exp2-domain
// softmax).  WO transposed via LDS tiles (coalesced 128B store segments).
// -------------------------------------------------------------------------
#define QSCALE 0.18033688011112042f

__global__ __launch_bounds__(256) void convert_kernel(
    const float* __restrict__ X,  const float* __restrict__ WQ,
    const float* __restrict__ WK, const float* __restrict__ WV,
    const float* __restrict__ WO,
    bf16* __restrict__ Xb, bf16* __restrict__ WQb, bf16* __restrict__ WKb,
    bf16* __restrict__ WVb, bf16* __restrict__ WOt)
{
    __shared__ float T[64][65];
    const int blk = blockIdx.x;
    if (blk < 7168) {
        const int t = blk * 256 + threadIdx.x;
        if (t < 1048576) {                         // X
            float4 v = ((const float4*)X)[t];
            u64 pk = (u64)f2bf(v.x) | ((u64)f2bf(v.y) << 16)
                   | ((u64)f2bf(v.z) << 32) | ((u64)f2bf(v.w) << 48);
            *(u64*)(Xb + 4 * (size_t)t) = pk;
        } else if (t < 1310720) {                  // WQ (scaled)
            int i = t - 1048576;
            float4 v = ((const float4*)WQ)[i];
            u64 pk = (u64)f2bf(v.x * QSCALE) | ((u64)f2bf(v.y * QSCALE) << 16)
                   | ((u64)f2bf(v.z * QSCALE) << 32) | ((u64)f2bf(v.w * QSCALE) << 48);
            *(u64*)(WQb + 4 * (size_t)i) = pk;
        } else if (t < 1572864) {                  // WK
            int i = t - 1310720;
            float4 v = ((const float4*)WK)[i];
            u64 pk = (u64)f2bf(v.x) | ((u64)f2bf(v.y) << 16)
                   | ((u64)f2bf(v.z) << 32) | ((u64)f2bf(v.w) << 48);
            *(u64*)(WKb + 4 * (size_t)i) = pk;
        } else {                                   // WV
            int i = t - 1572864;
            float4 v = ((const float4*)WV)[i];
            u64 pk = (u64)f2bf(v.x) | ((u64)f2bf(v.y) << 16)
                   | ((u64)f2bf(v.z) << 32) | ((u64)f2bf(v.w) << 48);
            *(u64*)(WVb + 4 * (size_t)i) = pk;
        }
    } else {                                       // WO transpose tile 64x64
        const int tile = blk - 7168;               // 0..255
        const int he0 = (tile & 15) * 64, d0 = (tile >> 4) * 64;
        const int tid = threadIdx.x;
        const int row = tid >> 2, c0 = (tid & 3) * 16;
        #pragma unroll
        for (int u = 0; u < 4; ++u) {
            float4 v = *(const float4*)(WO + (size_t)(he0 + row) * DM + d0 + c0 + u * 4);
            T[row][c0 + u * 4 + 0] = v.x;
            T[row][c0 + u * 4 + 1] = v.y;
            T[row][c0 + u * 4 + 2] = v.z;
            T[row][c0 + u * 4 + 3] = v.w;
        }
        __syncthreads();
        bf16 tmp[16];
        #pragma unroll
        for (int j = 0; j < 16; ++j) tmp[j] = f2bf(T[c0 + j][row]);
        *(short8*)(WOt + (size_t)(d0 + row) * DM + he0 + c0)     = *(short8*)&tmp[0];
        *(short8*)(WOt + (size_t)(d0 + row) * DM + he0 + c0 + 8) = *(short8*)&tmp[8];
    }
}

// -------------------------------------------------------------------------
// Merged projections, double-buffered staging (64 KB LDS), one launch:
//  id<512 : Q/K (mode=id&1): A=W rows(he), B=X rows(token).
//  id>=512: V  : A=X rows(s), B=WV rows(he).  8B packed stores everywhere.
// -------------------------------------------------------------------------
__global__ __launch_bounds__(256) void proj_kernel(
    const bf16* __restrict__ Xb, const bf16* __restrict__ WQb,
    const bf16* __restrict__ WKb, const bf16* __restrict__ WVb,
    bf16* __restrict__ qbuf, bf16* __restrict__ kbuf, bf16* __restrict__ vt)
{
    __shared__ char lds[65536];

    const int id = blockIdx.x;
    const int tid = threadIdx.x, wave = tid >> 6, lane = tid & 63;
    const int tx = lane & 15, quad = lane >> 4;
    const int wm = (wave >> 1) * 64, wn = (wave & 1) * 64;

    int mode, am0, bn0, bb = 0;
    const bf16 *Aop, *Bop;
    if (id < 512) {
        mode = id & 1;                    // 0=Q, 1=K
        int rem = id >> 1;
        bn0 = (rem & 31) * 128;           // token rows (B)
        am0 = (rem >> 5) * 128;           // he rows (A)
        Aop = (mode ? WKb : WQb) + (size_t)am0 * DM;
        Bop = Xb + (size_t)bn0 * DM;
    } else {
        mode = 2;
        int rem = id - 512;
        bb = rem & 1;
        rem >>= 1;
        bn0 = (rem & 7) * 128;            // he rows (B)
        am0 = (rem >> 3) * 128;           // s rows (A, within batch)
        Aop = Xb + ((size_t)bb * S_LEN + am0) * DM;
        Bop = WVb + (size_t)bn0 * DM;
    }

    f32x4 acc[4][4] = {};

    // prologue: stage k-slice 0 into buffer 0
    {
        char* As = lds;
        char* Bs = lds + 16384;
        #pragma unroll
        for (int r = 0; r < 4; ++r) {
            int slot = r * 256 + tid;
            int row = slot >> 3, g = slot & 7, gl = g ^ (row & 7);
            gload_lds16(Aop + (size_t)row * DM + gl * 8, As + r * 4096 + wave * 1024);
            gload_lds16(Bop + (size_t)row * DM + gl * 8, Bs + r * 4096 + wave * 1024);
        }
    }

    for (int kt = 0; kt < 16; ++kt) {
        char* As = lds + (kt & 1) * 32768;
        char* Bs = As + 16384;
        __syncthreads();                       // current buffer ready

        if (kt < 15) {                         // prefetch next k-slice
            char* An = lds + ((kt + 1) & 1) * 32768;
            char* Bn = An + 16384;
            const int k0 = (kt + 1) * 64;
            #pragma unroll
            for (int r = 0; r < 4; ++r) {
                int slot = r * 256 + tid;
                int row = slot >> 3, g = slot & 7, gl = g ^ (row & 7);
                gload_lds16(Aop + (size_t)row * DM + k0 + gl * 8,
                            An + r * 4096 + wave * 1024);
                gload_lds16(Bop + (size_t)row * DM + k0 + gl * 8,
                            Bn + r * 4096 + wave * 1024);
            }
        }

        #pragma unroll
        for (int ks = 0; ks < 2; ++ks) {
            const int swz = ((ks * 4 + quad) ^ (tx & 7)) * 16;
            short8 af[4], bfr[4];
            #pragma unroll
            for (int mt = 0; mt < 4; ++mt)
                af[mt] = *(const short8*)(As + (wm + mt * 16 + tx) * 128 + swz);
            #pragma unroll
            for (int nt = 0; nt < 4; ++nt)
                bfr[nt] = *(const short8*)(Bs + (wn + nt * 16 + tx) * 128 + swz);
            #pragma unroll
            for (int mt = 0; mt < 4; ++mt)
                #pragma unroll
                for (int nt = 0; nt < 4; ++nt)
                    acc[mt][nt] = __builtin_amdgcn_mfma_f32_16x16x32_bf16(
                        af[mt], bfr[nt], acc[mt][nt], 0, 0, 0);
        }
    }

    if (mode < 2) {
        bf16* outb = mode ? kbuf : qbuf;
        #pragma unroll
        for (int mt = 0; mt < 4; ++mt)
            #pragma unroll
            for (int nt = 0; nt < 4; ++nt) {
                int heG  = am0 + wm + mt * 16 + quad * 4;    // + r in reg
                int tokG = bn0 + wn + nt * 16 + tx;
                int b = tokG >> 11, s = tokG & 2047;
                int h = heG >> 6, e0 = heG & 63;
                *(u64*)(outb + ((size_t)(b * NH + h) * S_LEN + s) * DH + e0) =
                    pack4(acc[mt][nt]);
            }
    } else {
        #pragma unroll
        for (int mt = 0; mt < 4; ++mt)
            #pragma unroll
            for (int nt = 0; nt < 4; ++nt) {
                int sG  = am0 + wm + mt * 16 + quad * 4;     // + r in reg
                int heG = bn0 + wn + nt * 16 + tx;
                *(u64*)(vt + ((size_t)bb * DM + heG) * S_LEN + sG) =
                    pack4(acc[mt][nt]);
            }
    }
}

// -------------------------------------------------------------------------
// Flash attention.  Q-tile 64 (4 waves x 16 q), K-tile 64, dbuf K/V
// (32 KB LDS).  Grid 1024 = 4 blocks/CU fully resident; balanced mapping
// (every resident quartet sums to 66 iterations).  S^T via 16x16x32 MFMA;
// fixed-base exp2 softmax (no online max); PV via chained 16x16x16 MFMA
// straight from registers.  Causal diagonal is block-uniform (kmax = qb).
// Epilogue strips use the LDS buffer NOT holding the final tile.
// -------------------------------------------------------------------------
__global__ __launch_bounds__(256) void flash_kernel(
    const bf16* __restrict__ qbuf, const bf16* __restrict__ kbuf,
    const bf16* __restrict__ vtb, bf16* __restrict__ attn)
{
    __shared__ char lds[32768];

    const int i  = blockIdx.x;
    const int bh = i & 31;
    const int j  = i >> 5;
    const int qb = (i < 512) ? (31 - j) : (j - 16);  // heavy-first, paired
    const int tid = threadIdx.x, wave = tid >> 6, lane = tid & 63;
    const int tx = lane & 15, quad = lane >> 4;
    const int sw = tx & 7;

    const bf16* Qg = qbuf + (size_t)bh * S_LEN * DH + (size_t)qb * 64 * DH;
    const bf16* Kg = kbuf + (size_t)bh * S_LEN * DH;
    const bf16* Vg = vtb  + (size_t)bh * DH * S_LEN;

    // Q fragments straight from global: B-frag = 16B contiguous e per lane
    short8 bq[2];
    #pragma unroll
    for (int es = 0; es < 2; ++es)
        bq[es] = *(const short8*)(Qg + (size_t)(wave * 16 + tx) * DH +
                                  (es * 4 + quad) * 8);

    f32x4 oacc[4] = {};
    float l_part = 0.0f;

    const int kmax = qb;                       // block-uniform causal bound
    const int qg0  = qb * 64 + wave * 16 + tx;

    // stage k-tile 0 into buffer 0 (K: lds+0, V: lds+8192)
    #pragma unroll
    for (int r = 0; r < 2; ++r) {
        int slot = r * 256 + tid;
        int row = slot >> 3, g = slot & 7, gl = g ^ (row & 7);
        gload_lds16(Kg + (size_t)row * DH + gl * 8, lds + r * 4096 + wave * 1024);
        gload_lds16(Vg + (size_t)row * S_LEN + gl * 8,
                    lds + 8192 + r * 4096 + wave * 1024);
    }

    for (int kt64 = 0; kt64 <= kmax; ++kt64) {
        char* Kc = lds + (kt64 & 1) * 16384;
        char* Vc = Kc + 8192;
        __syncthreads();                       // current buffer ready

        if (kt64 < kmax) {                     // prefetch next tile
            char* Kn = lds + ((kt64 + 1) & 1) * 16384;
            char* Vn = Kn + 8192;
            #pragma unroll
            for (int r = 0; r < 2; ++r) {
                int slot = r * 256 + tid;
                int row = slot >> 3, g = slot & 7, gl = g ^ (row & 7);
                gload_lds16(Kg + ((size_t)(kt64 + 1) * 64 + row) * DH + gl * 8,
                            Kn + r * 4096 + wave * 1024);
                gload_lds16(Vg + (size_t)row * S_LEN + (kt64 + 1) * 64 + gl * 8,
                            Vn + r * 4096 + wave * 1024);
            }
        }

        // S^T = K * Q^T   (D[m=k][n=q])
        f32x4 st[4] = {};
        #pragma unroll
        for (int es = 0; es < 2; ++es) {
            #pragma unroll
            for (int kt = 0; kt < 4; ++kt) {
                short8 ak = *(const short8*)(Kc + (kt * 16 + tx) * 128 +
                                             (((es * 4 + quad) ^ sw) * 16));
                st[kt] = __builtin_amdgcn_mfma_f32_16x16x32_bf16(
                    ak, bq[es], st[kt], 0, 0, 0);
            }
        }

        if (kt64 == kmax) {                    // causal mask on diagonal tile
            #pragma unroll
            for (int kt = 0; kt < 4; ++kt)
                #pragma unroll
                for (int r = 0; r < 4; ++r)
                    if (kt64 * 64 + kt * 16 + quad * 4 + r > qg0)
                        st[kt][r] = -1e30f;
        }

        // fixed-base softmax: p = 2^s; pack P into 16x16x16 B-frags
        s16x4 pb[4];
        float rs = 0.0f;
        #pragma unroll
        for (int kt = 0; kt < 4; ++kt) {
            #pragma unroll
            for (int r = 0; r < 4; ++r) {
                float p = fast_exp2(st[kt][r]);
                st[kt][r] = p;
                rs += p;
            }
            pb[kt] = pack4s(st[kt]);
        }
        l_part += rs;

        // O^T += V^T * P, chained 16x16x16 MFMA (P from registers)
        #pragma unroll
        for (int kt = 0; kt < 4; ++kt) {
            #pragma unroll
            for (int et = 0; et < 4; ++et) {
                s16x4 av = *(const s16x4*)(Vc + (et * 16 + tx) * 128 +
                             (((kt * 2 + (quad >> 1)) ^ sw) * 16) + (quad & 1) * 8);
                oacc[et] = __builtin_amdgcn_mfma_f32_16x16x16bf16_1k(
                    av, pb[kt], oacc[et], 0, 0, 0);
            }
        }
    }

    // epilogue: reduce l across quads, divide, pack, un-transpose via LDS
    // strips in the buffer NOT holding the final tile (no barrier needed:
    // that buffer was released by the final top-of-loop __syncthreads).
    const int b = bh >> 4, h = bh & 15;
    char* Pw = lds + ((kmax & 1) ^ 1) * 16384 + wave * 2048;
    float l = l_part;
    l += __shfl_xor(l, 16);
    l += __shfl_xor(l, 32);
    float inv = 1.0f / l;
    #pragma unroll
    for (int et = 0; et < 4; ++et) {
        unsigned lo = pack2(oacc[et][0] * inv, oacc[et][1] * inv);
        unsigned hi = pack2(oacc[et][2] * inv, oacc[et][3] * inv);
        int eg = et * 2 + (quad >> 1);
        *(uint2*)(Pw + tx * 128 + ((eg ^ sw) * 16) + (quad & 1) * 8) =
            make_uint2(lo, hi);
    }
    asm volatile("s_waitcnt lgkmcnt(0)" ::: "memory");

    const int s = qb * 64 + wave * 16 + tx;
    bf16* op = attn + ((size_t)b * S_LEN + s) * DM + h * DH;
    #pragma unroll
    for (int c2 = 0; c2 < 2; ++c2) {
        int c = quad + c2 * 4;
        short8 v = *(const short8*)(Pw + tx * 128 + ((c ^ sw) * 16));
        *(short8*)(op + c * 8) = v;
    }
}

// -------------------------------------------------------------------------
// Output projection: out = attn(bf16) * WOt^T, fp32 out.  128x64 tiles,
// 512 blocks, double-buffered (48 KB LDS), wave tile 32x64.
// -------------------------------------------------------------------------
__global__ __launch_bounds__(256) void out_proj_kernel(
    const bf16* __restrict__ A, const bf16* __restrict__ Bt,
    float* __restrict__ out)
{
    __shared__ char lds[49152];

    const int m0 = blockIdx.x * 128, n0 = blockIdx.y * 64;
    const int tid = threadIdx.x, wave = tid >> 6, lane = tid & 63;
    const int tx = lane & 15, quad = lane >> 4;
    const int wm = wave * 32;

    f32x4 acc[2][4] = {};

    {
        char* As = lds;
        char* Bs = lds + 16384;
        #pragma unroll
        for (int r = 0; r < 4; ++r) {
            int slot = r * 256 + tid;
            int row = slot >> 3, g = slot & 7, gl = g ^ (row & 7);
            gload_lds16(A + (size_t)(m0 + row) * DM + gl * 8,
                        As + r * 4096 + wave * 1024);
        }
        #pragma unroll
        for (int r = 0; r < 2; ++r) {
            int slot = r * 256 + tid;
            int row = slot >> 3, g = slot & 7, gl = g ^ (row & 7);
            gload_lds16(Bt + (size_t)(n0 + row) * DM + gl * 8,
                        Bs + r * 4096 + wave * 1024);
        }
    }

    for (int kt = 0; kt < 16; ++kt) {
        char* As = lds + (kt & 1) * 24576;
        char* Bs = As + 16384;
        __syncthreads();

        if (kt < 15) {
            char* An = lds + ((kt + 1) & 1) * 24576;
            char* Bn = An + 16384;
            const int k0 = (kt + 1) * 64;
            #pragma unroll
            for (int r = 0; r < 4; ++r) {
                int slot = r * 256 + tid;
                int row = slot >> 3, g = slot & 7, gl = g ^ (row & 7);
                gload_lds16(A + (size_t)(m0 + row) * DM + k0 + gl * 8,
                            An + r * 4096 + wave * 1024);
            }
            #pragma unroll
            for (int r = 0; r < 2; ++r) {
                int slot = r * 256 + tid;
                int row = slot >> 3, g = slot & 7, gl = g ^ (row & 7);
                gload_lds16(Bt + (size_t)(n0 + row) * DM + k0 + gl * 8,
                            Bn + r * 4096 + wave * 1024);
            }
        }

        #pragma unroll
        for (int ks = 0; ks < 2; ++ks) {
            const int swz = ((ks * 4 + quad) ^ (tx & 7)) * 16;
            short8 af[2], bfr[4];
            #pragma unroll
            for (int mt = 0; mt < 2; ++mt)
                af[mt] = *(const short8*)(As + (wm + mt * 16 + tx) * 128 + swz);
            #pragma unroll
            for (int nt = 0; nt < 4; ++nt)
                bfr[nt] = *(const short8*)(Bs + (nt * 16 + tx) * 128 + swz);
            #pragma unroll
            for (int mt = 0; mt < 2; ++mt)
                #pragma unroll
                for (int nt = 0; nt < 4; ++nt)
                    acc[mt][nt] = __builtin_amdgcn_mfma_f32_16x16x32_bf16(
                        af[mt], bfr[nt], acc[mt][nt], 0, 0, 0);
        }
    }

    #pragma unroll
    for (int mt = 0; mt < 2; ++mt)
        #pragma unroll
        for (int nt = 0; nt < 4; ++nt)
            #pragma unroll
            for (int r = 0; r < 4; ++r) {
                int mG = m0 + wm + mt * 16 + quad * 4 + r;
                int nG = n0 + nt * 16 + tx;
                out[(size_t)mG * DM + nG] = acc[mt][nt][r];
            }
}

// -------------------------------------------------------------------------
extern "C" void kernel_launch(void* const* d_in, const int* in_sizes, int n_in,
                              void* d_out, int out_size, void* d_ws, size_t ws_size,
                              hipStream_t stream) {
    const float* X  = (const float*)d_in[0];
    const float* WQ = (const float*)d_in[1];
    const float* WK = (const float*)d_in[2];
    const float* WV = (const float*)d_in[3];
    const float* WO = (const float*)d_in[4];
    float* out = (float*)d_out;

    char* ws = (char*)d_ws;
    bf16* Xb   = (bf16*)(ws);                          // 8 MB
    bf16* WQb  = (bf16*)(ws + (8u  << 20));            // 2 MB
    bf16* WKb  = (bf16*)(ws + (10u << 20));            // 2 MB
    bf16* WVb  = (bf16*)(ws + (12u << 20));            // 2 MB
    bf16* WOt  = (bf16*)(ws + (14u << 20));            // 2 MB
    bf16* qbuf = (bf16*)(ws + (16u << 20));            // 8 MB
    bf16* kbuf = (bf16*)(ws + (24u << 20));            // 8 MB
    bf16* vt   = (bf16*)(ws + (32u << 20));            // 8 MB
    bf16* attn = (bf16*)(ws + (40u << 20));            // 8 MB

    convert_kernel<<<7424, 256, 0, stream>>>(X, WQ, WK, WV, WO,
                                             Xb, WQb, WKb, WVb, WOt);
    proj_kernel<<<768, 256, 0, stream>>>(Xb, WQb, WKb, WVb, qbuf, kbuf, vt);
    flash_kernel<<<1024, 256, 0, stream>>>(qbuf, kbuf, vt, attn);
    out_proj_kernel<<<dim3(32, 16), 256, 0, stream>>>(attn, WOt, out);
}